// Round 12
// baseline (201.076 us; speedup 1.0000x reference)
//
#include <hip/hip_runtime.h>

#define EPSI 1e-5f

typedef __attribute__((ext_vector_type(8))) short bf16x8;
typedef __attribute__((ext_vector_type(4))) float f32x4;

__device__ __forceinline__ float lrelu(float x) { return x > 0.f ? x : 0.01f * x; }

// float -> bf16 bits, round-to-nearest-even (header-free)
__device__ __forceinline__ unsigned short f2bf(float x) {
    unsigned int u = __float_as_uint(x);
    return (unsigned short)((u + 0x7fffu + ((u >> 16) & 1u)) >> 16);
}
// bf16 pair (packed in uint) -> floats
__device__ __forceinline__ float bflo(unsigned int v) { return __uint_as_float(v << 16); }
__device__ __forceinline__ float bfhi(unsigned int v) { return __uint_as_float(v & 0xFFFF0000u); }
__device__ __forceinline__ unsigned int pack2(float a, float b) {
    return (unsigned int)f2bf(a) | ((unsigned int)f2bf(b) << 16);
}
__device__ __forceinline__ bf16x8 pack8(float4 a, float4 b) {
    union { unsigned short u[8]; bf16x8 v; } p;
    p.u[0] = f2bf(a.x); p.u[1] = f2bf(a.y); p.u[2] = f2bf(a.z); p.u[3] = f2bf(a.w);
    p.u[4] = f2bf(b.x); p.u[5] = f2bf(b.y); p.u[6] = f2bf(b.z); p.u[7] = f2bf(b.w);
    return p.v;
}

// 8 bf16 (one dwordx4) -> 8 floats. v[c] = x0 chan c, v[4+c] = x1 chan c
// for packed layout [..][x][4chan].
struct Oct { float v[8]; };
__device__ __forceinline__ Oct unpack8(uint4 r) {
    Oct o;
    o.v[0] = bflo(r.x); o.v[1] = bfhi(r.x); o.v[2] = bflo(r.y); o.v[3] = bfhi(r.y);
    o.v[4] = bflo(r.z); o.v[5] = bfhi(r.z); o.v[6] = bflo(r.w); o.v[7] = bfhi(r.w);
    return o;
}

// Block-wide sum of (a,b). blockDim.x == 256.
__device__ __forceinline__ float2 block_reduce_sum2(float a, float b) {
    #pragma unroll
    for (int off = 1; off < 64; off <<= 1) {
        a += __shfl_xor(a, off, 64);
        b += __shfl_xor(b, off, 64);
    }
    __shared__ float lds[8];
    const int t = threadIdx.x;
    if ((t & 63) == 0) { lds[2 * (t >> 6)] = a; lds[2 * (t >> 6) + 1] = b; }
    __syncthreads();
    a = lds[0] + lds[2] + lds[4] + lds[6];
    b = lds[1] + lds[3] + lds[5] + lds[7];
    return make_float2(a, b);
}

// Packed intermediate layouts (bf16):
//   h1p: [n][4 icq][64y][64x][4c]   (65536/sample)
//   h2p: [n][8 icq][32y][32x][4c]   (32768/sample)
//   h3p: [n][16icq][16y][16x][4c]   (16384/sample)
//   h4 : [n][128co][64px] standard  (feeds MFMA GEMM)

// ---------------- K1: conv1(3->16) + IN + lrelu -> packed bf16 -------------------
// grid: B=256 blocks, 1024 threads, 4 px/thread, acc[16][4] in VGPRs.
__global__ __launch_bounds__(1024, 1) void k1_conv_in(const float* __restrict__ x,
                                                      const float* __restrict__ w1,
                                                      unsigned short* __restrict__ h1) {
    const int n = blockIdx.x;
    const int t = threadIdx.x;
    __shared__ float red[16][16][2]; // [wave][co][s1/s2]
    __shared__ float msc[16][2];     // [co][mean/scale]
    const float* xn = x + (size_t)n * 49152;
    float acc[16][4];
    #pragma unroll
    for (int j = 0; j < 16; ++j)
        #pragma unroll
        for (int q = 0; q < 4; ++q) acc[j][q] = 0.f;
    #pragma unroll 1
    for (int ic = 0; ic < 3; ++ic) {
        const float* p = xn + ic * 16384;
        float2 v0[4], v1[4];
        #pragma unroll
        for (int q = 0; q < 4; ++q) {
            const int idx = t + 1024 * q;
            const int oy = idx >> 6, ox = idx & 63;
            v0[q] = ((const float2*)(p + (2 * oy) * 128))[ox];
            v1[q] = ((const float2*)(p + (2 * oy + 1) * 128))[ox];
        }
        #pragma unroll
        for (int j = 0; j < 16; ++j) {
            const float4 wv = *(const float4*)(w1 + j * 12 + ic * 4);  // uniform -> SGPR
            #pragma unroll
            for (int q = 0; q < 4; ++q)
                acc[j][q] += v0[q].x * wv.x + v0[q].y * wv.y + v1[q].x * wv.z + v1[q].y * wv.w;
        }
    }
    const int w = t >> 6, l = t & 63;
    #pragma unroll
    for (int j = 0; j < 16; ++j) {
        float s1 = acc[j][0] + acc[j][1] + acc[j][2] + acc[j][3];
        float s2 = acc[j][0] * acc[j][0] + acc[j][1] * acc[j][1] +
                   acc[j][2] * acc[j][2] + acc[j][3] * acc[j][3];
        #pragma unroll
        for (int off = 1; off < 64; off <<= 1) {
            s1 += __shfl_xor(s1, off, 64);
            s2 += __shfl_xor(s2, off, 64);
        }
        if (l == 0) { red[w][j][0] = s1; red[w][j][1] = s2; }
    }
    __syncthreads();
    if (t < 16) {
        float s1 = 0.f, s2 = 0.f;
        #pragma unroll
        for (int ww = 0; ww < 16; ++ww) { s1 += red[ww][t][0]; s2 += red[ww][t][1]; }
        const float mean = s1 * (1.f / 4096.f);
        const float var = s2 * (1.f / 4096.f) - mean * mean;
        msc[t][0] = mean; msc[t][1] = rsqrtf(var + EPSI);
    }
    __syncthreads();
    unsigned short* on = h1 + (size_t)n * 65536;
    #pragma unroll
    for (int q = 0; q < 4; ++q) {
        const int px = t + 1024 * q;
        #pragma unroll
        for (int q4 = 0; q4 < 4; ++q4) {
            const float n0 = lrelu((acc[4 * q4 + 0][q] - msc[4 * q4 + 0][0]) * msc[4 * q4 + 0][1]);
            const float n1 = lrelu((acc[4 * q4 + 1][q] - msc[4 * q4 + 1][0]) * msc[4 * q4 + 1][1]);
            const float n2 = lrelu((acc[4 * q4 + 2][q] - msc[4 * q4 + 2][0]) * msc[4 * q4 + 2][1]);
            const float n3 = lrelu((acc[4 * q4 + 3][q] - msc[4 * q4 + 3][0]) * msc[4 * q4 + 3][1]);
            uint2 u; u.x = pack2(n0, n1); u.y = pack2(n2, n3);
            *(uint2*)(on + ((size_t)q4 * 4096 + px) * 4) = u;   // 8B coalesced store
        }
    }
}

// ---------------- K2: conv2(16->32) + IN + lrelu, packed in/out ------------------
// grid: B*2 = 512 blocks, 512 threads, 2 px/thread, acc[16][2].
// Packed layout: one dwordx4 = 2 x-positions x 4 channels (16B) per patch row.
__global__ __launch_bounds__(512, 2) void k2_conv_in(const unsigned short* __restrict__ h1,
                                                     const float* __restrict__ w2,
                                                     unsigned short* __restrict__ h2) {
    const int n = blockIdx.x >> 1, cg = blockIdx.x & 1;
    const int t = threadIdx.x;
    __shared__ float red[8][16][2];
    __shared__ float msc[16][2];
    const unsigned short* h1n = h1 + (size_t)n * 65536;
    const int oy0 = t >> 5, ox0 = t & 31;    // px0 = t; px1 = t+512 (oy+16)
    float acc[16][2];
    #pragma unroll
    for (int j = 0; j < 16; ++j) { acc[j][0] = 0.f; acc[j][1] = 0.f; }
    #pragma unroll 1
    for (int q = 0; q < 4; ++q) {
        const unsigned short* base = h1n + q * 16384;
        const uint4 r0a = *(const uint4*)(base + ((2 * oy0) * 64 + 2 * ox0) * 4);
        const uint4 r1a = *(const uint4*)(base + ((2 * oy0 + 1) * 64 + 2 * ox0) * 4);
        const uint4 r0b = *(const uint4*)(base + ((2 * oy0 + 32) * 64 + 2 * ox0) * 4);
        const uint4 r1b = *(const uint4*)(base + ((2 * oy0 + 33) * 64 + 2 * ox0) * 4);
        const Oct a0 = unpack8(r0a), a1 = unpack8(r1a);
        const Oct b0 = unpack8(r0b), b1 = unpack8(r1b);
        #pragma unroll
        for (int j = 0; j < 16; ++j) {
            #pragma unroll
            for (int c = 0; c < 4; ++c) {
                const float4 wv = *(const float4*)(w2 + (cg * 16 + j) * 144 + (q * 4 + c) * 4);
                acc[j][0] += a0.v[c] * wv.x + a0.v[4 + c] * wv.y + a1.v[c] * wv.z + a1.v[4 + c] * wv.w;
                acc[j][1] += b0.v[c] * wv.x + b0.v[4 + c] * wv.y + b1.v[c] * wv.z + b1.v[4 + c] * wv.w;
            }
        }
    }
    const int w = t >> 6, l = t & 63;
    #pragma unroll
    for (int j = 0; j < 16; ++j) {
        float s1 = acc[j][0] + acc[j][1];
        float s2 = acc[j][0] * acc[j][0] + acc[j][1] * acc[j][1];
        #pragma unroll
        for (int off = 1; off < 64; off <<= 1) {
            s1 += __shfl_xor(s1, off, 64);
            s2 += __shfl_xor(s2, off, 64);
        }
        if (l == 0) { red[w][j][0] = s1; red[w][j][1] = s2; }
    }
    __syncthreads();
    if (t < 16) {
        float s1 = 0.f, s2 = 0.f;
        #pragma unroll
        for (int ww = 0; ww < 8; ++ww) { s1 += red[ww][t][0]; s2 += red[ww][t][1]; }
        const float mean = s1 * (1.f / 1024.f);
        const float var = s2 * (1.f / 1024.f) - mean * mean;
        msc[t][0] = mean; msc[t][1] = rsqrtf(var + EPSI);
    }
    __syncthreads();
    unsigned short* on = h2 + (size_t)n * 32768;
    #pragma unroll
    for (int j4 = 0; j4 < 4; ++j4) {
        float p0[4], p1[4];
        #pragma unroll
        for (int c = 0; c < 4; ++c) {
            const int j = 4 * j4 + c;
            p0[c] = lrelu((acc[j][0] - msc[j][0]) * msc[j][1]);
            p1[c] = lrelu((acc[j][1] - msc[j][0]) * msc[j][1]);
        }
        uint2 u0; u0.x = pack2(p0[0], p0[1]); u0.y = pack2(p0[2], p0[3]);
        uint2 u1; u1.x = pack2(p1[0], p1[1]); u1.y = pack2(p1[2], p1[3]);
        *(uint2*)(on + ((size_t)(cg * 4 + j4) * 1024 + t) * 4) = u0;
        *(uint2*)(on + ((size_t)(cg * 4 + j4) * 1024 + t + 512) * 4) = u1;
    }
}

// ---------------- K3: conv3(32->64) + IN + lrelu, packed in/out ------------------
// grid: B*4 = 1024 blocks, 256 threads, 1 px/thread, acc[16].
__global__ __launch_bounds__(256, 4) void k3_conv_in(const unsigned short* __restrict__ h2,
                                                     const float* __restrict__ w3,
                                                     unsigned short* __restrict__ h3) {
    const int n = blockIdx.x >> 2, cg = blockIdx.x & 3;
    const int t = threadIdx.x;
    __shared__ float red[4][16][2];
    __shared__ float msc[16][2];
    const unsigned short* h2n = h2 + (size_t)n * 32768;
    const int oy = t >> 4, ox = t & 15;
    float acc[16];
    #pragma unroll
    for (int j = 0; j < 16; ++j) acc[j] = 0.f;
    #pragma unroll 1
    for (int q = 0; q < 8; ++q) {
        const unsigned short* base = h2n + q * 4096;
        const uint4 r0 = *(const uint4*)(base + ((2 * oy) * 32 + 2 * ox) * 4);
        const uint4 r1 = *(const uint4*)(base + ((2 * oy + 1) * 32 + 2 * ox) * 4);
        const Oct a0 = unpack8(r0), a1 = unpack8(r1);
        #pragma unroll
        for (int j = 0; j < 16; ++j) {
            #pragma unroll
            for (int c = 0; c < 4; ++c) {
                const float4 wv = *(const float4*)(w3 + (size_t)(cg * 16 + j) * 128 + (q * 4 + c) * 4);
                acc[j] += a0.v[c] * wv.x + a0.v[4 + c] * wv.y + a1.v[c] * wv.z + a1.v[4 + c] * wv.w;
            }
        }
    }
    const int w = t >> 6, l = t & 63;
    #pragma unroll
    for (int j = 0; j < 16; ++j) {
        float s1 = acc[j], s2 = acc[j] * acc[j];
        #pragma unroll
        for (int off = 1; off < 64; off <<= 1) {
            s1 += __shfl_xor(s1, off, 64);
            s2 += __shfl_xor(s2, off, 64);
        }
        if (l == 0) { red[w][j][0] = s1; red[w][j][1] = s2; }
    }
    __syncthreads();
    if (t < 16) {
        const float s1 = red[0][t][0] + red[1][t][0] + red[2][t][0] + red[3][t][0];
        const float s2 = red[0][t][1] + red[1][t][1] + red[2][t][1] + red[3][t][1];
        const float mean = s1 * (1.f / 256.f);
        const float var = s2 * (1.f / 256.f) - mean * mean;
        msc[t][0] = mean; msc[t][1] = rsqrtf(var + EPSI);
    }
    __syncthreads();
    unsigned short* on = h3 + (size_t)n * 16384;
    #pragma unroll
    for (int j4 = 0; j4 < 4; ++j4) {
        float p0[4];
        #pragma unroll
        for (int c = 0; c < 4; ++c) {
            const int j = 4 * j4 + c;
            p0[c] = lrelu((acc[j] - msc[j][0]) * msc[j][1]);
        }
        uint2 u; u.x = pack2(p0[0], p0[1]); u.y = pack2(p0[2], p0[3]);
        *(uint2*)(on + ((size_t)(cg * 4 + j4) * 256 + t) * 4) = u;
    }
}

// ---------------- K4: conv4(64->128) + IN + lrelu, packed in, std out ------------
// grid: B*4 = 1024 blocks, 256 threads (4 waves). Wave w: 8 co, lane = px (8x8).
__global__ __launch_bounds__(256, 4) void k4_conv_in(const unsigned short* __restrict__ h3,
                                                     const float* __restrict__ w4,
                                                     unsigned short* __restrict__ h4) {
    const int n = blockIdx.x >> 2, cg = blockIdx.x & 3;
    const int t = threadIdx.x;
    const int w = __builtin_amdgcn_readfirstlane(t >> 6);
    const int l = t & 63;
    const int oy = l >> 3, ox = l & 7;
    const unsigned short* h3n = h3 + (size_t)n * 16384;
    const float* wbase = w4 + (size_t)(cg * 32 + w * 8) * 256;
    float acc[8];
    #pragma unroll
    for (int jj = 0; jj < 8; ++jj) acc[jj] = 0.f;
    #pragma unroll 1
    for (int q = 0; q < 16; ++q) {
        const unsigned short* base = h3n + q * 1024;
        const uint4 r0 = *(const uint4*)(base + ((2 * oy) * 16 + 2 * ox) * 4);
        const uint4 r1 = *(const uint4*)(base + ((2 * oy + 1) * 16 + 2 * ox) * 4);
        const Oct a0 = unpack8(r0), a1 = unpack8(r1);
        #pragma unroll
        for (int jj = 0; jj < 8; ++jj) {
            #pragma unroll
            for (int c = 0; c < 4; ++c) {
                const float4 wv = *(const float4*)(wbase + jj * 256 + (q * 4 + c) * 4);  // SGPR
                acc[jj] += a0.v[c] * wv.x + a0.v[4 + c] * wv.y + a1.v[c] * wv.z + a1.v[4 + c] * wv.w;
            }
        }
    }
    unsigned short* on = h4 + (size_t)n * 8192;
    #pragma unroll
    for (int jj = 0; jj < 8; ++jj) {
        float s1 = acc[jj], s2 = acc[jj] * acc[jj];
        #pragma unroll
        for (int off = 1; off < 64; off <<= 1) {
            s1 += __shfl_xor(s1, off, 64);
            s2 += __shfl_xor(s2, off, 64);
        }
        const float mean = s1 * (1.f / 64.f);
        const float var = s2 * (1.f / 64.f) - mean * mean;
        const float sc = rsqrtf(var + EPSI);
        on[(cg * 32 + w * 8 + jj) * 64 + l] = f2bf(lrelu((acc[jj] - mean) * sc));
    }
}

// ---------------- K5: FC1 bf16 MFMA split-K GEMM (W converted in-staging) --------
// C[256,1024] = A[256,8192](bf16) x W[1024,8192]^T(fp32->bf16 on the fly).
// BM=BN=128, BK=64, SK=16 (K-chunk 512): grid = 16 tiles x 16 sk = 256 blocks.
__global__ __launch_bounds__(256, 2) void k5_fc1(const unsigned short* __restrict__ A,
                                                 const float* __restrict__ Wf,
                                                 float* __restrict__ Cp) {
    __shared__ unsigned short As[128 * 72];
    __shared__ unsigned short Bs[128 * 72];
    const int t = threadIdx.x;
    const int sk = blockIdx.x >> 4;          // 0..15
    const int tile = blockIdx.x & 15;        // mt*8 + nt
    const int mt = tile >> 3, nt = tile & 7;
    const int m0 = mt * 128, n0 = nt * 128;
    const int w = t >> 6, l = t & 63;
    const int wm = (w >> 1) * 64, wn = (w & 1) * 64;
    const int lr16 = l & 15, lk8 = (l >> 4) * 8;   // frag row / k-base (guide §3)
    const int srow = t >> 3, scol = (t & 7) * 8;   // staging row / col
    f32x4 acc[4][4];
    const f32x4 z = {0.f, 0.f, 0.f, 0.f};
    #pragma unroll
    for (int f = 0; f < 4; ++f)
        #pragma unroll
        for (int g = 0; g < 4; ++g) acc[f][g] = z;
    const int kbeg = sk * 512;
    #pragma unroll 1
    for (int kt = 0; kt < 8; ++kt) {
        const int kc = kbeg + kt * 64;
        bf16x8 av[4], bv[4];
        #pragma unroll
        for (int i = 0; i < 4; ++i) {
            av[i] = *(const bf16x8*)(A + (size_t)(m0 + srow + 32 * i) * 8192 + kc + scol);
            const float4 w0 = *(const float4*)(Wf + (size_t)(n0 + srow + 32 * i) * 8192 + kc + scol);
            const float4 w1 = *(const float4*)(Wf + (size_t)(n0 + srow + 32 * i) * 8192 + kc + scol + 4);
            bv[i] = pack8(w0, w1);
        }
        __syncthreads();   // previous tile's frag reads complete
        #pragma unroll
        for (int i = 0; i < 4; ++i) {
            *(bf16x8*)&As[(srow + 32 * i) * 72 + scol] = av[i];
            *(bf16x8*)&Bs[(srow + 32 * i) * 72 + scol] = bv[i];
        }
        __syncthreads();   // tile staged
        #pragma unroll
        for (int ks = 0; ks < 2; ++ks) {
            bf16x8 af[4], bfr[4];
            #pragma unroll
            for (int f = 0; f < 4; ++f)
                af[f] = *(const bf16x8*)&As[(wm + f * 16 + lr16) * 72 + ks * 32 + lk8];
            #pragma unroll
            for (int g = 0; g < 4; ++g)
                bfr[g] = *(const bf16x8*)&Bs[(wn + g * 16 + lr16) * 72 + ks * 32 + lk8];
            #pragma unroll
            for (int f = 0; f < 4; ++f)
                #pragma unroll
                for (int g = 0; g < 4; ++g)
                    acc[f][g] = __builtin_amdgcn_mfma_f32_16x16x32_bf16(af[f], bfr[g], acc[f][g], 0, 0, 0);
        }
    }
    // C/D layout (guide §3, m89-verified): col = l&15, row = (l>>4)*4 + reg
    const int orow = (l >> 4) * 4, ocol = l & 15;
    #pragma unroll
    for (int f = 0; f < 4; ++f) {
        #pragma unroll
        for (int g = 0; g < 4; ++g) {
            #pragma unroll
            for (int j = 0; j < 4; ++j) {
                const int m = m0 + wm + f * 16 + orow + j;
                const int n = n0 + wn + g * 16 + ocol;
                Cp[((size_t)sk * 256 + m) * 1024 + n] = acc[f][g][j];
            }
        }
    }
}

// ---------------- K6: fused split-K reduce + bias + lrelu + FC2 ------------------
__global__ __launch_bounds__(256) void k6_fc2(const float* __restrict__ Cp,
                                              const float* __restrict__ bias,
                                              const float* __restrict__ w,
                                              const float* __restrict__ b,
                                              float* __restrict__ out) {
    const int n = blockIdx.x, t = threadIdx.x;
    float part = 0.f;
    #pragma unroll
    for (int i = 0; i < 4; ++i) {
        const int nn = t + 256 * i;
        float s = 0.f;
        #pragma unroll
        for (int sk = 0; sk < 16; ++sk)
            s += Cp[((size_t)sk * 256 + n) * 1024 + nn];
        part += lrelu(s + bias[nn]) * w[nn];
    }
    const float2 red = block_reduce_sum2(part, 0.f);
    if (t == 0) out[n] = red.x + b[0];
}

extern "C" void kernel_launch(void* const* d_in, const int* in_sizes, int n_in,
                              void* d_out, int out_size, void* d_ws, size_t ws_size,
                              hipStream_t stream) {
    (void)in_sizes; (void)n_in; (void)out_size; (void)ws_size;
    const float* x    = (const float*)d_in[0];
    // labels (d_in[1]) and conv biases (d_in[3,5,7,9]) cancel exactly under InstanceNorm
    const float* w1   = (const float*)d_in[2];
    const float* w2   = (const float*)d_in[4];
    const float* w3   = (const float*)d_in[6];
    const float* w4   = (const float*)d_in[8];
    const float* fcw1 = (const float*)d_in[10];
    const float* fcb1 = (const float*)d_in[11];
    const float* fcw2 = (const float*)d_in[12];
    const float* fcb2 = (const float*)d_in[13];
    float* out = (float*)d_out;
    float* bufA = (float*)d_ws;                    // 16.7M floats (67 MB)
    float* bufB = bufA + 16777216;                 //  8.4M floats (33 MB)
    unsigned short* h1 = (unsigned short*)bufA;    // packed [4icq][4096][4]
    unsigned short* h2 = (unsigned short*)bufB;    // packed [8icq][1024][4]
    unsigned short* h3 = (unsigned short*)bufA;    // packed [16icq][256][4] (h1 dead)
    unsigned short* h4 = (unsigned short*)bufB;    // standard [128co][64px] (h2 dead)
    float* Cp = bufA;                              // 16*256*1024 fp32 (h3 dead at k5)
    k1_conv_in<<<256, 1024, 0, stream>>>(x, w1, h1);
    k2_conv_in<<<512, 512, 0, stream>>>(h1, w2, h2);
    k3_conv_in<<<1024, 256, 0, stream>>>(h2, w3, h3);
    k4_conv_in<<<1024, 256, 0, stream>>>(h3, w4, h4);
    k5_fc1<<<256, 256, 0, stream>>>(h4, fcw1, Cp);
    k6_fc2<<<256, 256, 0, stream>>>(Cp, fcb1, fcw2, fcb2, out);
}

// Round 13
// 92.556 us; speedup vs baseline: 2.1725x; 2.1725x over previous
//
#include <hip/hip_runtime.h>

#define EPSI 1e-5f

typedef __attribute__((ext_vector_type(8))) short bf16x8;
typedef __attribute__((ext_vector_type(4))) float f32x4;

__device__ __forceinline__ float lrelu(float x) { return x > 0.f ? x : 0.01f * x; }

// float -> bf16 bits, round-to-nearest-even (header-free)
__device__ __forceinline__ unsigned short f2bf(float x) {
    unsigned int u = __float_as_uint(x);
    return (unsigned short)((u + 0x7fffu + ((u >> 16) & 1u)) >> 16);
}
__device__ __forceinline__ float bflo(unsigned int v) { return __uint_as_float(v << 16); }
__device__ __forceinline__ float bfhi(unsigned int v) { return __uint_as_float(v & 0xFFFF0000u); }
__device__ __forceinline__ unsigned int pack2(float a, float b) {
    return (unsigned int)f2bf(a) | ((unsigned int)f2bf(b) << 16);
}
__device__ __forceinline__ bf16x8 pack8(float4 a, float4 b) {
    union { unsigned short u[8]; bf16x8 v; } p;
    p.u[0] = f2bf(a.x); p.u[1] = f2bf(a.y); p.u[2] = f2bf(a.z); p.u[3] = f2bf(a.w);
    p.u[4] = f2bf(b.x); p.u[5] = f2bf(b.y); p.u[6] = f2bf(b.z); p.u[7] = f2bf(b.w);
    return p.v;
}

// Block-wide sum of (a,b). blockDim.x == 256.
__device__ __forceinline__ float2 block_reduce_sum2(float a, float b) {
    #pragma unroll
    for (int off = 1; off < 64; off <<= 1) {
        a += __shfl_xor(a, off, 64);
        b += __shfl_xor(b, off, 64);
    }
    __shared__ float lds[8];
    const int t = threadIdx.x;
    if ((t & 63) == 0) { lds[2 * (t >> 6)] = a; lds[2 * (t >> 6) + 1] = b; }
    __syncthreads();
    a = lds[0] + lds[2] + lds[4] + lds[6];
    b = lds[1] + lds[3] + lds[5] + lds[7];
    return make_float2(a, b);
}

// Packed activation layouts (bf16): h1p [n][4icq][64y][64x][4c], h2p [n][8icq][32y][32x][4c],
// h3p [n][16icq][16y][16x][4c]; h4 standard [n][128co][64px] (feeds FC1 GEMM, co-major K).
// Conv GEMM k-order: k = icq*16 + row*8 + tx*4 + c  -> one 16B load per lane K-octet.

// ---------------- WPREP: reorder conv weights to bf16 wk[co][k] ------------------
// wk2 at off 0 (32x64), wk3 at 2048 (64x128), wk4 at 10240 (128x256).
__global__ __launch_bounds__(1024) void wprep(const float* __restrict__ w2,
                                              const float* __restrict__ w3,
                                              const float* __restrict__ w4,
                                              unsigned short* __restrict__ wk) {
    const int g = blockIdx.x * 1024 + threadIdx.x;
    if (g < 2048) {
        const int co = g >> 6, k = g & 63;
        const int ic = (k >> 4) * 4 + (k & 3), row = (k >> 3) & 1, tx = (k >> 2) & 1;
        wk[g] = f2bf(w2[co * 144 + ic * 4 + row * 2 + tx]);
    } else if (g < 10240) {
        const int e = g - 2048, co = e >> 7, k = e & 127;
        const int ic = (k >> 4) * 4 + (k & 3), row = (k >> 3) & 1, tx = (k >> 2) & 1;
        wk[g] = f2bf(w3[co * 128 + ic * 4 + row * 2 + tx]);
    } else if (g < 43008) {
        const int e = g - 10240, co = e >> 8, k = e & 255;
        const int ic = (k >> 4) * 4 + (k & 3), row = (k >> 3) & 1, tx = (k >> 2) & 1;
        wk[g] = f2bf(w4[co * 256 + ic * 4 + row * 2 + tx]);
    }
}

// ---------------- K1: conv1(3->16) + IN + lrelu -> packed bf16 (VALU) ------------
__global__ __launch_bounds__(1024, 1) void k1_conv_in(const float* __restrict__ x,
                                                      const float* __restrict__ w1,
                                                      unsigned short* __restrict__ h1) {
    const int n = blockIdx.x;
    const int t = threadIdx.x;
    __shared__ float red[16][16][2];
    __shared__ float msc[16][2];
    const float* xn = x + (size_t)n * 49152;
    float acc[16][4];
    #pragma unroll
    for (int j = 0; j < 16; ++j)
        #pragma unroll
        for (int q = 0; q < 4; ++q) acc[j][q] = 0.f;
    #pragma unroll 1
    for (int ic = 0; ic < 3; ++ic) {
        const float* p = xn + ic * 16384;
        float2 v0[4], v1[4];
        #pragma unroll
        for (int q = 0; q < 4; ++q) {
            const int idx = t + 1024 * q;
            const int oy = idx >> 6, ox = idx & 63;
            v0[q] = ((const float2*)(p + (2 * oy) * 128))[ox];
            v1[q] = ((const float2*)(p + (2 * oy + 1) * 128))[ox];
        }
        #pragma unroll
        for (int j = 0; j < 16; ++j) {
            const float4 wv = *(const float4*)(w1 + j * 12 + ic * 4);  // uniform -> SGPR
            #pragma unroll
            for (int q = 0; q < 4; ++q)
                acc[j][q] += v0[q].x * wv.x + v0[q].y * wv.y + v1[q].x * wv.z + v1[q].y * wv.w;
        }
    }
    const int w = t >> 6, l = t & 63;
    #pragma unroll
    for (int j = 0; j < 16; ++j) {
        float s1 = acc[j][0] + acc[j][1] + acc[j][2] + acc[j][3];
        float s2 = acc[j][0] * acc[j][0] + acc[j][1] * acc[j][1] +
                   acc[j][2] * acc[j][2] + acc[j][3] * acc[j][3];
        #pragma unroll
        for (int off = 1; off < 64; off <<= 1) {
            s1 += __shfl_xor(s1, off, 64);
            s2 += __shfl_xor(s2, off, 64);
        }
        if (l == 0) { red[w][j][0] = s1; red[w][j][1] = s2; }
    }
    __syncthreads();
    if (t < 16) {
        float s1 = 0.f, s2 = 0.f;
        #pragma unroll
        for (int ww = 0; ww < 16; ++ww) { s1 += red[ww][t][0]; s2 += red[ww][t][1]; }
        const float mean = s1 * (1.f / 4096.f);
        const float var = s2 * (1.f / 4096.f) - mean * mean;
        msc[t][0] = mean; msc[t][1] = rsqrtf(var + EPSI);
    }
    __syncthreads();
    unsigned short* on = h1 + (size_t)n * 65536;
    #pragma unroll
    for (int q = 0; q < 4; ++q) {
        const int px = t + 1024 * q;
        #pragma unroll
        for (int q4 = 0; q4 < 4; ++q4) {
            const float n0 = lrelu((acc[4 * q4 + 0][q] - msc[4 * q4 + 0][0]) * msc[4 * q4 + 0][1]);
            const float n1 = lrelu((acc[4 * q4 + 1][q] - msc[4 * q4 + 1][0]) * msc[4 * q4 + 1][1]);
            const float n2 = lrelu((acc[4 * q4 + 2][q] - msc[4 * q4 + 2][0]) * msc[4 * q4 + 2][1]);
            const float n3 = lrelu((acc[4 * q4 + 3][q] - msc[4 * q4 + 3][0]) * msc[4 * q4 + 3][1]);
            uint2 u; u.x = pack2(n0, n1); u.y = pack2(n2, n3);
            *(uint2*)(on + ((size_t)q4 * 4096 + px) * 4) = u;
        }
    }
}

// ---------------- K2M: conv2 as MFMA GEMM [32co x 64K x 1024px] + IN -------------
// Block = sample, 1024 thr (16 waves), wave = 64 px (4 groups of 16).
// acc[pg][cf] f32x4; C-row = co = cf*16+(l>>4)*4+reg, C-col = px-in-group = l&15.
__global__ __launch_bounds__(1024, 1) void k2m(const unsigned short* __restrict__ h1,
                                               const unsigned short* __restrict__ wk,
                                               unsigned short* __restrict__ h2) {
    const int n = blockIdx.x;
    const int t = threadIdx.x;
    const int w = t >> 6, l = t & 63;
    __shared__ float red[16][32][2];
    __shared__ float msc[32][2];
    const unsigned short* h1n = h1 + (size_t)n * 65536;
    // A-frags (weights): co = cf*16 + (l&15), k-slice ks*32 + (l>>4)*8
    bf16x8 af[2][2];
    #pragma unroll
    for (int cf = 0; cf < 2; ++cf)
        #pragma unroll
        for (int ks = 0; ks < 2; ++ks)
            af[cf][ks] = *(const bf16x8*)(wk + (cf * 16 + (l & 15)) * 64 + ks * 32 + (l >> 4) * 8);
    f32x4 acc[4][2];
    const f32x4 z = {0.f, 0.f, 0.f, 0.f};
    #pragma unroll
    for (int pg = 0; pg < 4; ++pg) { acc[pg][0] = z; acc[pg][1] = z; }
    const int row = (l >> 4) & 1, icq0 = (l >> 4) >> 1;
    #pragma unroll
    for (int pg = 0; pg < 4; ++pg) {
        const int oy = 2 * w + (pg >> 1);
        const int ox = (pg & 1) * 16 + (l & 15);
        #pragma unroll
        for (int ks = 0; ks < 2; ++ks) {
            const bf16x8 bv = *(const bf16x8*)(h1n + (ks * 2 + icq0) * 16384 + (2 * oy + row) * 256 + ox * 8);
            acc[pg][0] = __builtin_amdgcn_mfma_f32_16x16x32_bf16(af[0][ks], bv, acc[pg][0], 0, 0, 0);
            acc[pg][1] = __builtin_amdgcn_mfma_f32_16x16x32_bf16(af[1][ks], bv, acc[pg][1], 0, 0, 0);
        }
    }
    // IN stats: per co, sum over px. Butterfly over low-4 lane bits (px), LDS over waves.
    #pragma unroll
    for (int cf = 0; cf < 2; ++cf) {
        #pragma unroll
        for (int r = 0; r < 4; ++r) {
            float s1 = acc[0][cf][r] + acc[1][cf][r] + acc[2][cf][r] + acc[3][cf][r];
            float s2 = acc[0][cf][r] * acc[0][cf][r] + acc[1][cf][r] * acc[1][cf][r] +
                       acc[2][cf][r] * acc[2][cf][r] + acc[3][cf][r] * acc[3][cf][r];
            #pragma unroll
            for (int off = 1; off < 16; off <<= 1) {
                s1 += __shfl_xor(s1, off, 64);
                s2 += __shfl_xor(s2, off, 64);
            }
            if ((l & 15) == 0) {
                red[w][cf * 16 + (l >> 4) * 4 + r][0] = s1;
                red[w][cf * 16 + (l >> 4) * 4 + r][1] = s2;
            }
        }
    }
    __syncthreads();
    if (t < 32) {
        float s1 = 0.f, s2 = 0.f;
        #pragma unroll
        for (int ww = 0; ww < 16; ++ww) { s1 += red[ww][t][0]; s2 += red[ww][t][1]; }
        const float mean = s1 * (1.f / 1024.f);
        const float var = s2 * (1.f / 1024.f) - mean * mean;
        msc[t][0] = mean; msc[t][1] = rsqrtf(var + EPSI);
    }
    __syncthreads();
    unsigned short* on = h2 + (size_t)n * 32768;
    #pragma unroll
    for (int pg = 0; pg < 4; ++pg) {
        const int px = w * 64 + pg * 16 + (l & 15);
        #pragma unroll
        for (int cf = 0; cf < 2; ++cf) {
            const int co0 = cf * 16 + (l >> 4) * 4;
            float v[4];
            #pragma unroll
            for (int r = 0; r < 4; ++r)
                v[r] = lrelu((acc[pg][cf][r] - msc[co0 + r][0]) * msc[co0 + r][1]);
            uint2 u; u.x = pack2(v[0], v[1]); u.y = pack2(v[2], v[3]);
            *(uint2*)(on + ((size_t)(cf * 4 + (l >> 4)) * 1024 + px) * 4) = u;
        }
    }
}

// ---------------- K3M: conv3 as MFMA GEMM [64co x 128K x 256px] + IN -------------
// Block = sample, 1024 thr (16 waves), wave = one output row (16 px).
__global__ __launch_bounds__(1024, 1) void k3m(const unsigned short* __restrict__ h2,
                                               const unsigned short* __restrict__ wk,
                                               unsigned short* __restrict__ h3) {
    const int n = blockIdx.x;
    const int t = threadIdx.x;
    const int w = t >> 6, l = t & 63;
    __shared__ float red[16][64][2];
    __shared__ float msc[64][2];
    const unsigned short* h2n = h2 + (size_t)n * 32768;
    f32x4 acc[4];
    const f32x4 z = {0.f, 0.f, 0.f, 0.f};
    #pragma unroll
    for (int cf = 0; cf < 4; ++cf) acc[cf] = z;
    const int row = (l >> 4) & 1, icq0 = (l >> 4) >> 1;
    #pragma unroll
    for (int ks = 0; ks < 4; ++ks) {
        const bf16x8 bv = *(const bf16x8*)(h2n + (ks * 2 + icq0) * 4096 + (2 * w + row) * 128 + (l & 15) * 8);
        #pragma unroll
        for (int cf = 0; cf < 4; ++cf) {
            const bf16x8 af = *(const bf16x8*)(wk + (cf * 16 + (l & 15)) * 128 + ks * 32 + (l >> 4) * 8);
            acc[cf] = __builtin_amdgcn_mfma_f32_16x16x32_bf16(af, bv, acc[cf], 0, 0, 0);
        }
    }
    #pragma unroll
    for (int cf = 0; cf < 4; ++cf) {
        #pragma unroll
        for (int r = 0; r < 4; ++r) {
            float s1 = acc[cf][r], s2 = acc[cf][r] * acc[cf][r];
            #pragma unroll
            for (int off = 1; off < 16; off <<= 1) {
                s1 += __shfl_xor(s1, off, 64);
                s2 += __shfl_xor(s2, off, 64);
            }
            if ((l & 15) == 0) {
                red[w][cf * 16 + (l >> 4) * 4 + r][0] = s1;
                red[w][cf * 16 + (l >> 4) * 4 + r][1] = s2;
            }
        }
    }
    __syncthreads();
    if (t < 64) {
        float s1 = 0.f, s2 = 0.f;
        #pragma unroll
        for (int ww = 0; ww < 16; ++ww) { s1 += red[ww][t][0]; s2 += red[ww][t][1]; }
        const float mean = s1 * (1.f / 256.f);
        const float var = s2 * (1.f / 256.f) - mean * mean;
        msc[t][0] = mean; msc[t][1] = rsqrtf(var + EPSI);
    }
    __syncthreads();
    unsigned short* on = h3 + (size_t)n * 16384;
    const int px = w * 16 + (l & 15);
    #pragma unroll
    for (int cf = 0; cf < 4; ++cf) {
        const int co0 = cf * 16 + (l >> 4) * 4;
        float v[4];
        #pragma unroll
        for (int r = 0; r < 4; ++r)
            v[r] = lrelu((acc[cf][r] - msc[co0 + r][0]) * msc[co0 + r][1]);
        uint2 u; u.x = pack2(v[0], v[1]); u.y = pack2(v[2], v[3]);
        *(uint2*)(on + ((size_t)(cf * 4 + (l >> 4)) * 256 + px) * 4) = u;
    }
}

// ---------------- K4M: conv4 as MFMA GEMM [128co x 256K x 64px] + IN -------------
// Block = sample, 512 thr (8 waves): wave = (cfp = w&3 -> co-frags 2cfp,2cfp+1;
// khalf = w>>2 -> K-half). LDS partial combine, then khalf=1 waves do IN + store.
__global__ __launch_bounds__(512, 2) void k4m(const unsigned short* __restrict__ h3,
                                              const unsigned short* __restrict__ wk,
                                              unsigned short* __restrict__ h4) {
    const int n = blockIdx.x;
    const int t = threadIdx.x;
    const int w = t >> 6, l = t & 63;
    const int cfp = w & 3, khalf = w >> 2;
    __shared__ float ps[4][64][32];   // [cfp][lane][pg*8 + cfi*4 + r] = 32KB
    const unsigned short* h3n = h3 + (size_t)n * 16384;
    f32x4 acc[4][2];
    const f32x4 z = {0.f, 0.f, 0.f, 0.f};
    #pragma unroll
    for (int pg = 0; pg < 4; ++pg) { acc[pg][0] = z; acc[pg][1] = z; }
    const int row = (l >> 4) & 1, icq0 = (l >> 4) >> 1;
    const int oyb = (l & 15) >> 3, ox = l & 7;
    #pragma unroll
    for (int ksl = 0; ksl < 4; ++ksl) {
        const int ks = khalf * 4 + ksl;
        bf16x8 af0 = *(const bf16x8*)(wk + ((cfp * 2 + 0) * 16 + (l & 15)) * 256 + ks * 32 + (l >> 4) * 8);
        bf16x8 af1 = *(const bf16x8*)(wk + ((cfp * 2 + 1) * 16 + (l & 15)) * 256 + ks * 32 + (l >> 4) * 8);
        #pragma unroll
        for (int pg = 0; pg < 4; ++pg) {
            const int oy = pg * 2 + oyb;
            const bf16x8 bv = *(const bf16x8*)(h3n + (ks * 2 + icq0) * 1024 + (2 * oy + row) * 64 + ox * 8);
            acc[pg][0] = __builtin_amdgcn_mfma_f32_16x16x32_bf16(af0, bv, acc[pg][0], 0, 0, 0);
            acc[pg][1] = __builtin_amdgcn_mfma_f32_16x16x32_bf16(af1, bv, acc[pg][1], 0, 0, 0);
        }
    }
    if (khalf == 0) {
        #pragma unroll
        for (int pg = 0; pg < 4; ++pg)
            #pragma unroll
            for (int cfi = 0; cfi < 2; ++cfi)
                #pragma unroll
                for (int r = 0; r < 4; ++r)
                    ps[cfp][l][pg * 8 + cfi * 4 + r] = acc[pg][cfi][r];
    }
    __syncthreads();
    if (khalf == 1) {
        unsigned short* on = h4 + (size_t)n * 8192;
        #pragma unroll
        for (int cfi = 0; cfi < 2; ++cfi) {
            #pragma unroll
            for (int r = 0; r < 4; ++r) {
                float v[4];
                #pragma unroll
                for (int pg = 0; pg < 4; ++pg)
                    v[pg] = acc[pg][cfi][r] + ps[cfp][l][pg * 8 + cfi * 4 + r];
                float s1 = v[0] + v[1] + v[2] + v[3];
                float s2 = v[0] * v[0] + v[1] * v[1] + v[2] * v[2] + v[3] * v[3];
                #pragma unroll
                for (int off = 1; off < 16; off <<= 1) {
                    s1 += __shfl_xor(s1, off, 64);
                    s2 += __shfl_xor(s2, off, 64);
                }
                const float mean = s1 * (1.f / 64.f);
                const float var = s2 * (1.f / 64.f) - mean * mean;
                const float sc = rsqrtf(var + EPSI);
                const int co = (cfp * 2 + cfi) * 16 + (l >> 4) * 4 + r;
                #pragma unroll
                for (int pg = 0; pg < 4; ++pg)
                    on[co * 64 + pg * 16 + (l & 15)] = f2bf(lrelu((v[pg] - mean) * sc));
            }
        }
    }
}

// ---------------- K5: FC1 bf16 MFMA split-K GEMM (W converted in-staging) --------
__global__ __launch_bounds__(256, 2) void k5_fc1(const unsigned short* __restrict__ A,
                                                 const float* __restrict__ Wf,
                                                 float* __restrict__ Cp) {
    __shared__ unsigned short As[128 * 72];
    __shared__ unsigned short Bs[128 * 72];
    const int t = threadIdx.x;
    const int sk = blockIdx.x >> 4;          // 0..15
    const int tile = blockIdx.x & 15;
    const int mt = tile >> 3, nt = tile & 7;
    const int m0 = mt * 128, n0 = nt * 128;
    const int w = t >> 6, l = t & 63;
    const int wm = (w >> 1) * 64, wn = (w & 1) * 64;
    const int lr16 = l & 15, lk8 = (l >> 4) * 8;
    const int srow = t >> 3, scol = (t & 7) * 8;
    f32x4 acc[4][4];
    const f32x4 z = {0.f, 0.f, 0.f, 0.f};
    #pragma unroll
    for (int f = 0; f < 4; ++f)
        #pragma unroll
        for (int g = 0; g < 4; ++g) acc[f][g] = z;
    const int kbeg = sk * 512;
    #pragma unroll 1
    for (int kt = 0; kt < 8; ++kt) {
        const int kc = kbeg + kt * 64;
        bf16x8 av[4], bv[4];
        #pragma unroll
        for (int i = 0; i < 4; ++i) {
            av[i] = *(const bf16x8*)(A + (size_t)(m0 + srow + 32 * i) * 8192 + kc + scol);
            const float4 w0 = *(const float4*)(Wf + (size_t)(n0 + srow + 32 * i) * 8192 + kc + scol);
            const float4 w1 = *(const float4*)(Wf + (size_t)(n0 + srow + 32 * i) * 8192 + kc + scol + 4);
            bv[i] = pack8(w0, w1);
        }
        __syncthreads();
        #pragma unroll
        for (int i = 0; i < 4; ++i) {
            *(bf16x8*)&As[(srow + 32 * i) * 72 + scol] = av[i];
            *(bf16x8*)&Bs[(srow + 32 * i) * 72 + scol] = bv[i];
        }
        __syncthreads();
        #pragma unroll
        for (int ks = 0; ks < 2; ++ks) {
            bf16x8 af[4], bfr[4];
            #pragma unroll
            for (int f = 0; f < 4; ++f)
                af[f] = *(const bf16x8*)&As[(wm + f * 16 + lr16) * 72 + ks * 32 + lk8];
            #pragma unroll
            for (int g = 0; g < 4; ++g)
                bfr[g] = *(const bf16x8*)&Bs[(wn + g * 16 + lr16) * 72 + ks * 32 + lk8];
            #pragma unroll
            for (int f = 0; f < 4; ++f)
                #pragma unroll
                for (int g = 0; g < 4; ++g)
                    acc[f][g] = __builtin_amdgcn_mfma_f32_16x16x32_bf16(af[f], bfr[g], acc[f][g], 0, 0, 0);
        }
    }
    const int orow = (l >> 4) * 4, ocol = l & 15;
    #pragma unroll
    for (int f = 0; f < 4; ++f) {
        #pragma unroll
        for (int g = 0; g < 4; ++g) {
            #pragma unroll
            for (int j = 0; j < 4; ++j) {
                const int m = m0 + wm + f * 16 + orow + j;
                const int nn = n0 + wn + g * 16 + ocol;
                Cp[((size_t)sk * 256 + m) * 1024 + nn] = acc[f][g][j];
            }
        }
    }
}

// ---------------- K6: fused split-K reduce + bias + lrelu + FC2 ------------------
__global__ __launch_bounds__(256) void k6_fc2(const float* __restrict__ Cp,
                                              const float* __restrict__ bias,
                                              const float* __restrict__ w,
                                              const float* __restrict__ b,
                                              float* __restrict__ out) {
    const int n = blockIdx.x, t = threadIdx.x;
    float part = 0.f;
    #pragma unroll
    for (int i = 0; i < 4; ++i) {
        const int nn = t + 256 * i;
        float s = 0.f;
        #pragma unroll
        for (int sk = 0; sk < 16; ++sk)
            s += Cp[((size_t)sk * 256 + n) * 1024 + nn];
        part += lrelu(s + bias[nn]) * w[nn];
    }
    const float2 red = block_reduce_sum2(part, 0.f);
    if (t == 0) out[n] = red.x + b[0];
}

extern "C" void kernel_launch(void* const* d_in, const int* in_sizes, int n_in,
                              void* d_out, int out_size, void* d_ws, size_t ws_size,
                              hipStream_t stream) {
    (void)in_sizes; (void)n_in; (void)out_size; (void)ws_size;
    const float* x    = (const float*)d_in[0];
    // labels (d_in[1]) and conv biases (d_in[3,5,7,9]) cancel exactly under InstanceNorm
    const float* w1   = (const float*)d_in[2];
    const float* w2   = (const float*)d_in[4];
    const float* w3   = (const float*)d_in[6];
    const float* w4   = (const float*)d_in[8];
    const float* fcw1 = (const float*)d_in[10];
    const float* fcb1 = (const float*)d_in[11];
    const float* fcw2 = (const float*)d_in[12];
    const float* fcb2 = (const float*)d_in[13];
    float* out = (float*)d_out;
    float* bufA = (float*)d_ws;                    // 16.7M floats
    float* bufB = bufA + 16777216;                 //  8.4M floats
    unsigned short* h1 = (unsigned short*)bufA;    // packed, 16.7M shorts
    unsigned short* h2 = (unsigned short*)bufB;    // packed, 8.4M shorts
    unsigned short* h3 = (unsigned short*)bufA;    // packed, 4.2M shorts (h1 dead)
    unsigned short* h4 = (unsigned short*)bufB;    // standard, 2.1M shorts (h2 dead)
    unsigned short* wk = (unsigned short*)bufB + 12582912;  // 43008 shorts, clear of h2/h4
    float* Cp = bufA;                              // 16*256*1024 fp32 (h3 dead at k5)
    wprep<<<42, 1024, 0, stream>>>(w2, w3, w4, wk);
    k1_conv_in<<<256, 1024, 0, stream>>>(x, w1, h1);
    k2m<<<256, 1024, 0, stream>>>(h1, wk, h2);
    k3m<<<256, 1024, 0, stream>>>(h2, wk + 2048, h3);
    k4m<<<256, 512, 0, stream>>>(h3, wk + 10240, h4);
    k5_fc1<<<256, 256, 0, stream>>>(h4, fcw1, Cp);
    k6_fc2<<<256, 256, 0, stream>>>(Cp, fcb1, fcw2, fcb2, out);
}

// Round 14
// 83.859 us; speedup vs baseline: 2.3978x; 1.1037x over previous
//
#include <hip/hip_runtime.h>

#define EPSI 1e-5f

typedef __attribute__((ext_vector_type(8))) short bf16x8;
typedef __attribute__((ext_vector_type(4))) float f32x4;

__device__ __forceinline__ float lrelu(float x) { return x > 0.f ? x : 0.01f * x; }

// float -> bf16 bits, round-to-nearest-even (header-free)
__device__ __forceinline__ unsigned short f2bf(float x) {
    unsigned int u = __float_as_uint(x);
    return (unsigned short)((u + 0x7fffu + ((u >> 16) & 1u)) >> 16);
}
__device__ __forceinline__ unsigned int pack2(float a, float b) {
    return (unsigned int)f2bf(a) | ((unsigned int)f2bf(b) << 16);
}
__device__ __forceinline__ bf16x8 pack8(float4 a, float4 b) {
    union { unsigned short u[8]; bf16x8 v; } p;
    p.u[0] = f2bf(a.x); p.u[1] = f2bf(a.y); p.u[2] = f2bf(a.z); p.u[3] = f2bf(a.w);
    p.u[4] = f2bf(b.x); p.u[5] = f2bf(b.y); p.u[6] = f2bf(b.z); p.u[7] = f2bf(b.w);
    return p.v;
}

// Block-wide sum of (a,b). blockDim.x == 256.
__device__ __forceinline__ float2 block_reduce_sum2(float a, float b) {
    #pragma unroll
    for (int off = 1; off < 64; off <<= 1) {
        a += __shfl_xor(a, off, 64);
        b += __shfl_xor(b, off, 64);
    }
    __shared__ float lds[8];
    const int t = threadIdx.x;
    if ((t & 63) == 0) { lds[2 * (t >> 6)] = a; lds[2 * (t >> 6) + 1] = b; }
    __syncthreads();
    a = lds[0] + lds[2] + lds[4] + lds[6];
    b = lds[1] + lds[3] + lds[5] + lds[7];
    return make_float2(a, b);
}

// Packed activation layouts (bf16): h1p [n][4icq][64y][64x][4c]; LDS h2s [8icq][32y][32x][4c],
// h3s [16icq][16y][16x][4c]; h4 standard [n][128co][64px] (feeds FC1 GEMM).
// Conv GEMM k-order: k = icq*16 + row*8 + tx*4 + c  -> one 16B load per lane K-octet.

// ---------------- WPREP: reorder conv weights to bf16 wk[co][k] ------------------
// wk2 at off 0 (32x64), wk3 at 2048 (64x128), wk4 at 10240 (128x256).
__global__ __launch_bounds__(1024) void wprep(const float* __restrict__ w2,
                                              const float* __restrict__ w3,
                                              const float* __restrict__ w4,
                                              unsigned short* __restrict__ wk) {
    const int g = blockIdx.x * 1024 + threadIdx.x;
    if (g < 2048) {
        const int co = g >> 6, k = g & 63;
        const int ic = (k >> 4) * 4 + (k & 3), row = (k >> 3) & 1, tx = (k >> 2) & 1;
        wk[g] = f2bf(w2[co * 144 + ic * 4 + row * 2 + tx]);
    } else if (g < 10240) {
        const int e = g - 2048, co = e >> 7, k = e & 127;
        const int ic = (k >> 4) * 4 + (k & 3), row = (k >> 3) & 1, tx = (k >> 2) & 1;
        wk[g] = f2bf(w3[co * 128 + ic * 4 + row * 2 + tx]);
    } else if (g < 43008) {
        const int e = g - 10240, co = e >> 8, k = e & 255;
        const int ic = (k >> 4) * 4 + (k & 3), row = (k >> 3) & 1, tx = (k >> 2) & 1;
        wk[g] = f2bf(w4[co * 256 + ic * 4 + row * 2 + tx]);
    }
}

// ---------------- K1: conv1(3->16) + IN + lrelu -> packed bf16 (VALU) ------------
__global__ __launch_bounds__(1024, 1) void k1_conv_in(const float* __restrict__ x,
                                                      const float* __restrict__ w1,
                                                      unsigned short* __restrict__ h1) {
    const int n = blockIdx.x;
    const int t = threadIdx.x;
    __shared__ float red[16][16][2];
    __shared__ float msc[16][2];
    const float* xn = x + (size_t)n * 49152;
    float acc[16][4];
    #pragma unroll
    for (int j = 0; j < 16; ++j)
        #pragma unroll
        for (int q = 0; q < 4; ++q) acc[j][q] = 0.f;
    #pragma unroll 1
    for (int ic = 0; ic < 3; ++ic) {
        const float* p = xn + ic * 16384;
        float2 v0[4], v1[4];
        #pragma unroll
        for (int q = 0; q < 4; ++q) {
            const int idx = t + 1024 * q;
            const int oy = idx >> 6, ox = idx & 63;
            v0[q] = ((const float2*)(p + (2 * oy) * 128))[ox];
            v1[q] = ((const float2*)(p + (2 * oy + 1) * 128))[ox];
        }
        #pragma unroll
        for (int j = 0; j < 16; ++j) {
            const float4 wv = *(const float4*)(w1 + j * 12 + ic * 4);  // uniform -> SGPR
            #pragma unroll
            for (int q = 0; q < 4; ++q)
                acc[j][q] += v0[q].x * wv.x + v0[q].y * wv.y + v1[q].x * wv.z + v1[q].y * wv.w;
        }
    }
    const int w = t >> 6, l = t & 63;
    #pragma unroll
    for (int j = 0; j < 16; ++j) {
        float s1 = acc[j][0] + acc[j][1] + acc[j][2] + acc[j][3];
        float s2 = acc[j][0] * acc[j][0] + acc[j][1] * acc[j][1] +
                   acc[j][2] * acc[j][2] + acc[j][3] * acc[j][3];
        #pragma unroll
        for (int off = 1; off < 64; off <<= 1) {
            s1 += __shfl_xor(s1, off, 64);
            s2 += __shfl_xor(s2, off, 64);
        }
        if (l == 0) { red[w][j][0] = s1; red[w][j][1] = s2; }
    }
    __syncthreads();
    if (t < 16) {
        float s1 = 0.f, s2 = 0.f;
        #pragma unroll
        for (int ww = 0; ww < 16; ++ww) { s1 += red[ww][t][0]; s2 += red[ww][t][1]; }
        const float mean = s1 * (1.f / 4096.f);
        const float var = s2 * (1.f / 4096.f) - mean * mean;
        msc[t][0] = mean; msc[t][1] = rsqrtf(var + EPSI);
    }
    __syncthreads();
    unsigned short* on = h1 + (size_t)n * 65536;
    #pragma unroll
    for (int q = 0; q < 4; ++q) {
        const int px = t + 1024 * q;
        #pragma unroll
        for (int q4 = 0; q4 < 4; ++q4) {
            const float n0 = lrelu((acc[4 * q4 + 0][q] - msc[4 * q4 + 0][0]) * msc[4 * q4 + 0][1]);
            const float n1 = lrelu((acc[4 * q4 + 1][q] - msc[4 * q4 + 1][0]) * msc[4 * q4 + 1][1]);
            const float n2 = lrelu((acc[4 * q4 + 2][q] - msc[4 * q4 + 2][0]) * msc[4 * q4 + 2][1]);
            const float n3 = lrelu((acc[4 * q4 + 3][q] - msc[4 * q4 + 3][0]) * msc[4 * q4 + 3][1]);
            uint2 u; u.x = pack2(n0, n1); u.y = pack2(n2, n3);
            *(uint2*)(on + ((size_t)q4 * 4096 + px) * 4) = u;
        }
    }
}

// ---------------- K234: conv2+conv3+conv4 fused, per-sample block ----------------
// 1024 thr (16 waves), 1 block/CU. h2 (64KB) and h3 (32KB) live in LDS only —
// removes 50MB of HBM round trips vs separate kernels. Arithmetic identical to
// R13's k2m/k3m/k4m (absmax must not change).
__global__ __launch_bounds__(1024, 1) void k234(const unsigned short* __restrict__ h1,
                                                const unsigned short* __restrict__ wk,
                                                unsigned short* __restrict__ h4) {
    const int n = blockIdx.x;
    const int t = threadIdx.x;
    const int w = t >> 6, l = t & 63;
    __shared__ unsigned short h2s[32768];   // 64KB packed [8icq][32y][32x][4c]
    __shared__ unsigned short h3s[16384];   // 32KB packed [16icq][16y][16x][4c]
    __shared__ float ps[4][64][32];         // 32KB phase-C partials
    __shared__ float red[16][64][2];        // 8KB
    __shared__ float msc[64][2];
    const unsigned short* h1n = h1 + (size_t)n * 65536;

    // ======== Phase A: conv2 [32co x 64K x 1024px] -> h2s ========
    {
        const unsigned short* wk2 = wk;
        bf16x8 af[2][2];
        #pragma unroll
        for (int cf = 0; cf < 2; ++cf)
            #pragma unroll
            for (int ks = 0; ks < 2; ++ks)
                af[cf][ks] = *(const bf16x8*)(wk2 + (cf * 16 + (l & 15)) * 64 + ks * 32 + (l >> 4) * 8);
        f32x4 acc[4][2];
        const f32x4 z = {0.f, 0.f, 0.f, 0.f};
        #pragma unroll
        for (int pg = 0; pg < 4; ++pg) { acc[pg][0] = z; acc[pg][1] = z; }
        const int row = (l >> 4) & 1, icq0 = (l >> 4) >> 1;
        #pragma unroll
        for (int pg = 0; pg < 4; ++pg) {
            const int oy = 2 * w + (pg >> 1);
            const int ox = (pg & 1) * 16 + (l & 15);
            #pragma unroll
            for (int ks = 0; ks < 2; ++ks) {
                const bf16x8 bv = *(const bf16x8*)(h1n + (ks * 2 + icq0) * 16384 + (2 * oy + row) * 256 + ox * 8);
                acc[pg][0] = __builtin_amdgcn_mfma_f32_16x16x32_bf16(af[0][ks], bv, acc[pg][0], 0, 0, 0);
                acc[pg][1] = __builtin_amdgcn_mfma_f32_16x16x32_bf16(af[1][ks], bv, acc[pg][1], 0, 0, 0);
            }
        }
        #pragma unroll
        for (int cf = 0; cf < 2; ++cf) {
            #pragma unroll
            for (int r = 0; r < 4; ++r) {
                float s1 = acc[0][cf][r] + acc[1][cf][r] + acc[2][cf][r] + acc[3][cf][r];
                float s2 = acc[0][cf][r] * acc[0][cf][r] + acc[1][cf][r] * acc[1][cf][r] +
                           acc[2][cf][r] * acc[2][cf][r] + acc[3][cf][r] * acc[3][cf][r];
                #pragma unroll
                for (int off = 1; off < 16; off <<= 1) {
                    s1 += __shfl_xor(s1, off, 64);
                    s2 += __shfl_xor(s2, off, 64);
                }
                if ((l & 15) == 0) {
                    red[w][cf * 16 + (l >> 4) * 4 + r][0] = s1;
                    red[w][cf * 16 + (l >> 4) * 4 + r][1] = s2;
                }
            }
        }
        __syncthreads();
        if (t < 32) {
            float s1 = 0.f, s2 = 0.f;
            #pragma unroll
            for (int ww = 0; ww < 16; ++ww) { s1 += red[ww][t][0]; s2 += red[ww][t][1]; }
            const float mean = s1 * (1.f / 1024.f);
            const float var = s2 * (1.f / 1024.f) - mean * mean;
            msc[t][0] = mean; msc[t][1] = rsqrtf(var + EPSI);
        }
        __syncthreads();
        #pragma unroll
        for (int pg = 0; pg < 4; ++pg) {
            const int px = w * 64 + pg * 16 + (l & 15);
            #pragma unroll
            for (int cf = 0; cf < 2; ++cf) {
                const int co0 = cf * 16 + (l >> 4) * 4;
                float v[4];
                #pragma unroll
                for (int r = 0; r < 4; ++r)
                    v[r] = lrelu((acc[pg][cf][r] - msc[co0 + r][0]) * msc[co0 + r][1]);
                uint2 u; u.x = pack2(v[0], v[1]); u.y = pack2(v[2], v[3]);
                *(uint2*)(&h2s[((cf * 4 + (l >> 4)) * 1024 + px) * 4]) = u;
            }
        }
    }
    __syncthreads();

    // ======== Phase B: conv3 [64co x 128K x 256px], h2s -> h3s ========
    {
        const unsigned short* wk3 = wk + 2048;
        f32x4 acc[4];
        const f32x4 z = {0.f, 0.f, 0.f, 0.f};
        #pragma unroll
        for (int cf = 0; cf < 4; ++cf) acc[cf] = z;
        const int row = (l >> 4) & 1, icq0 = (l >> 4) >> 1;
        #pragma unroll
        for (int ks = 0; ks < 4; ++ks) {
            const bf16x8 bv = *(const bf16x8*)(&h2s[(ks * 2 + icq0) * 4096 + (2 * w + row) * 128 + (l & 15) * 8]);
            #pragma unroll
            for (int cf = 0; cf < 4; ++cf) {
                const bf16x8 af = *(const bf16x8*)(wk3 + (cf * 16 + (l & 15)) * 128 + ks * 32 + (l >> 4) * 8);
                acc[cf] = __builtin_amdgcn_mfma_f32_16x16x32_bf16(af, bv, acc[cf], 0, 0, 0);
            }
        }
        #pragma unroll
        for (int cf = 0; cf < 4; ++cf) {
            #pragma unroll
            for (int r = 0; r < 4; ++r) {
                float s1 = acc[cf][r], s2 = acc[cf][r] * acc[cf][r];
                #pragma unroll
                for (int off = 1; off < 16; off <<= 1) {
                    s1 += __shfl_xor(s1, off, 64);
                    s2 += __shfl_xor(s2, off, 64);
                }
                if ((l & 15) == 0) {
                    red[w][cf * 16 + (l >> 4) * 4 + r][0] = s1;
                    red[w][cf * 16 + (l >> 4) * 4 + r][1] = s2;
                }
            }
        }
        __syncthreads();
        if (t < 64) {
            float s1 = 0.f, s2 = 0.f;
            #pragma unroll
            for (int ww = 0; ww < 16; ++ww) { s1 += red[ww][t][0]; s2 += red[ww][t][1]; }
            const float mean = s1 * (1.f / 256.f);
            const float var = s2 * (1.f / 256.f) - mean * mean;
            msc[t][0] = mean; msc[t][1] = rsqrtf(var + EPSI);
        }
        __syncthreads();
        const int px = w * 16 + (l & 15);
        #pragma unroll
        for (int cf = 0; cf < 4; ++cf) {
            const int co0 = cf * 16 + (l >> 4) * 4;
            float v[4];
            #pragma unroll
            for (int r = 0; r < 4; ++r)
                v[r] = lrelu((acc[cf][r] - msc[co0 + r][0]) * msc[co0 + r][1]);
            uint2 u; u.x = pack2(v[0], v[1]); u.y = pack2(v[2], v[3]);
            *(uint2*)(&h3s[((cf * 4 + (l >> 4)) * 256 + px) * 4]) = u;
        }
    }
    __syncthreads();

    // ======== Phase C: conv4 [128co x 256K x 64px], h3s -> h4 (waves 0-7) ========
    {
        const unsigned short* wk4 = wk + 10240;
        const int cfp = w & 3, khalf = (w >> 2) & 1;
        f32x4 acc[4][2];
        const f32x4 z = {0.f, 0.f, 0.f, 0.f};
        #pragma unroll
        for (int pg = 0; pg < 4; ++pg) { acc[pg][0] = z; acc[pg][1] = z; }
        const int row = (l >> 4) & 1, icq0 = (l >> 4) >> 1;
        const int oyb = (l & 15) >> 3, ox = l & 7;
        if (w < 8) {
            #pragma unroll
            for (int ksl = 0; ksl < 4; ++ksl) {
                const int ks = khalf * 4 + ksl;
                bf16x8 af0 = *(const bf16x8*)(wk4 + ((cfp * 2 + 0) * 16 + (l & 15)) * 256 + ks * 32 + (l >> 4) * 8);
                bf16x8 af1 = *(const bf16x8*)(wk4 + ((cfp * 2 + 1) * 16 + (l & 15)) * 256 + ks * 32 + (l >> 4) * 8);
                #pragma unroll
                for (int pg = 0; pg < 4; ++pg) {
                    const int oy = pg * 2 + oyb;
                    const bf16x8 bv = *(const bf16x8*)(&h3s[(ks * 2 + icq0) * 1024 + (2 * oy + row) * 64 + ox * 8]);
                    acc[pg][0] = __builtin_amdgcn_mfma_f32_16x16x32_bf16(af0, bv, acc[pg][0], 0, 0, 0);
                    acc[pg][1] = __builtin_amdgcn_mfma_f32_16x16x32_bf16(af1, bv, acc[pg][1], 0, 0, 0);
                }
            }
        }
        if (w < 4) {   // khalf == 0
            #pragma unroll
            for (int pg = 0; pg < 4; ++pg)
                #pragma unroll
                for (int cfi = 0; cfi < 2; ++cfi)
                    #pragma unroll
                    for (int r = 0; r < 4; ++r)
                        ps[cfp][l][pg * 8 + cfi * 4 + r] = acc[pg][cfi][r];
        }
        __syncthreads();
        if (w >= 4 && w < 8) {   // khalf == 1: combine + IN + store
            unsigned short* on = h4 + (size_t)n * 8192;
            #pragma unroll
            for (int cfi = 0; cfi < 2; ++cfi) {
                #pragma unroll
                for (int r = 0; r < 4; ++r) {
                    float v[4];
                    #pragma unroll
                    for (int pg = 0; pg < 4; ++pg)
                        v[pg] = acc[pg][cfi][r] + ps[cfp][l][pg * 8 + cfi * 4 + r];
                    float s1 = v[0] + v[1] + v[2] + v[3];
                    float s2 = v[0] * v[0] + v[1] * v[1] + v[2] * v[2] + v[3] * v[3];
                    #pragma unroll
                    for (int off = 1; off < 16; off <<= 1) {
                        s1 += __shfl_xor(s1, off, 64);
                        s2 += __shfl_xor(s2, off, 64);
                    }
                    const float mean = s1 * (1.f / 64.f);
                    const float var = s2 * (1.f / 64.f) - mean * mean;
                    const float sc = rsqrtf(var + EPSI);
                    const int co = (cfp * 2 + cfi) * 16 + (l >> 4) * 4 + r;
                    #pragma unroll
                    for (int pg = 0; pg < 4; ++pg)
                        on[co * 64 + pg * 16 + (l & 15)] = f2bf(lrelu((v[pg] - mean) * sc));
                }
            }
        }
    }
}

// ---------------- K5: FC1 bf16 MFMA split-K GEMM (W converted in-staging) --------
__global__ __launch_bounds__(256, 2) void k5_fc1(const unsigned short* __restrict__ A,
                                                 const float* __restrict__ Wf,
                                                 float* __restrict__ Cp) {
    __shared__ unsigned short As[128 * 72];
    __shared__ unsigned short Bs[128 * 72];
    const int t = threadIdx.x;
    const int sk = blockIdx.x >> 4;          // 0..15
    const int tile = blockIdx.x & 15;
    const int mt = tile >> 3, nt = tile & 7;
    const int m0 = mt * 128, n0 = nt * 128;
    const int w = t >> 6, l = t & 63;
    const int wm = (w >> 1) * 64, wn = (w & 1) * 64;
    const int lr16 = l & 15, lk8 = (l >> 4) * 8;
    const int srow = t >> 3, scol = (t & 7) * 8;
    f32x4 acc[4][4];
    const f32x4 z = {0.f, 0.f, 0.f, 0.f};
    #pragma unroll
    for (int f = 0; f < 4; ++f)
        #pragma unroll
        for (int g = 0; g < 4; ++g) acc[f][g] = z;
    const int kbeg = sk * 512;
    #pragma unroll 1
    for (int kt = 0; kt < 8; ++kt) {
        const int kc = kbeg + kt * 64;
        bf16x8 av[4], bv[4];
        #pragma unroll
        for (int i = 0; i < 4; ++i) {
            av[i] = *(const bf16x8*)(A + (size_t)(m0 + srow + 32 * i) * 8192 + kc + scol);
            const float4 w0 = *(const float4*)(Wf + (size_t)(n0 + srow + 32 * i) * 8192 + kc + scol);
            const float4 w1 = *(const float4*)(Wf + (size_t)(n0 + srow + 32 * i) * 8192 + kc + scol + 4);
            bv[i] = pack8(w0, w1);
        }
        __syncthreads();
        #pragma unroll
        for (int i = 0; i < 4; ++i) {
            *(bf16x8*)&As[(srow + 32 * i) * 72 + scol] = av[i];
            *(bf16x8*)&Bs[(srow + 32 * i) * 72 + scol] = bv[i];
        }
        __syncthreads();
        #pragma unroll
        for (int ks = 0; ks < 2; ++ks) {
            bf16x8 af[4], bfr[4];
            #pragma unroll
            for (int f = 0; f < 4; ++f)
                af[f] = *(const bf16x8*)&As[(wm + f * 16 + lr16) * 72 + ks * 32 + lk8];
            #pragma unroll
            for (int g = 0; g < 4; ++g)
                bfr[g] = *(const bf16x8*)&Bs[(wn + g * 16 + lr16) * 72 + ks * 32 + lk8];
            #pragma unroll
            for (int f = 0; f < 4; ++f)
                #pragma unroll
                for (int g = 0; g < 4; ++g)
                    acc[f][g] = __builtin_amdgcn_mfma_f32_16x16x32_bf16(af[f], bfr[g], acc[f][g], 0, 0, 0);
        }
    }
    const int orow = (l >> 4) * 4, ocol = l & 15;
    #pragma unroll
    for (int f = 0; f < 4; ++f) {
        #pragma unroll
        for (int g = 0; g < 4; ++g) {
            #pragma unroll
            for (int j = 0; j < 4; ++j) {
                const int m = m0 + wm + f * 16 + orow + j;
                const int nn = n0 + wn + g * 16 + ocol;
                Cp[((size_t)sk * 256 + m) * 1024 + nn] = acc[f][g][j];
            }
        }
    }
}

// ---------------- K6: fused split-K reduce + bias + lrelu + FC2 ------------------
__global__ __launch_bounds__(256) void k6_fc2(const float* __restrict__ Cp,
                                              const float* __restrict__ bias,
                                              const float* __restrict__ w,
                                              const float* __restrict__ b,
                                              float* __restrict__ out) {
    const int n = blockIdx.x, t = threadIdx.x;
    float part = 0.f;
    #pragma unroll
    for (int i = 0; i < 4; ++i) {
        const int nn = t + 256 * i;
        float s = 0.f;
        #pragma unroll
        for (int sk = 0; sk < 16; ++sk)
            s += Cp[((size_t)sk * 256 + n) * 1024 + nn];
        part += lrelu(s + bias[nn]) * w[nn];
    }
    const float2 red = block_reduce_sum2(part, 0.f);
    if (t == 0) out[n] = red.x + b[0];
}

extern "C" void kernel_launch(void* const* d_in, const int* in_sizes, int n_in,
                              void* d_out, int out_size, void* d_ws, size_t ws_size,
                              hipStream_t stream) {
    (void)in_sizes; (void)n_in; (void)out_size; (void)ws_size;
    const float* x    = (const float*)d_in[0];
    // labels (d_in[1]) and conv biases (d_in[3,5,7,9]) cancel exactly under InstanceNorm
    const float* w1   = (const float*)d_in[2];
    const float* w2   = (const float*)d_in[4];
    const float* w3   = (const float*)d_in[6];
    const float* w4   = (const float*)d_in[8];
    const float* fcw1 = (const float*)d_in[10];
    const float* fcb1 = (const float*)d_in[11];
    const float* fcw2 = (const float*)d_in[12];
    const float* fcb2 = (const float*)d_in[13];
    float* out = (float*)d_out;
    float* bufA = (float*)d_ws;                    // 16.7M floats
    float* bufB = bufA + 16777216;                 //  8.4M floats
    unsigned short* h1 = (unsigned short*)bufA;    // packed, 16.7M shorts
    unsigned short* h4 = (unsigned short*)bufB;    // standard, 2.1M shorts
    unsigned short* wk = (unsigned short*)bufB + 12582912;  // 43008 shorts, clear of h4
    float* Cp = bufA;                              // 16*256*1024 fp32 (h1 dead at k5)
    wprep<<<42, 1024, 0, stream>>>(w2, w3, w4, wk);
    k1_conv_in<<<256, 1024, 0, stream>>>(x, w1, h1);
    k234<<<256, 1024, 0, stream>>>(h1, wk, h4);
    k5_fc1<<<256, 256, 0, stream>>>(h4, fcw1, Cp);
    k6_fc2<<<256, 256, 0, stream>>>(Cp, fcb1, fcw2, fcb2, out);
}

// Round 15
// 76.516 us; speedup vs baseline: 2.6279x; 1.0960x over previous
//
#include <hip/hip_runtime.h>

#define EPSI 1e-5f

typedef __attribute__((ext_vector_type(8))) short bf16x8;
typedef __attribute__((ext_vector_type(4))) float f32x4;

__device__ __forceinline__ float lrelu(float x) { return x > 0.f ? x : 0.01f * x; }

// float -> bf16 bits, round-to-nearest-even (header-free)
__device__ __forceinline__ unsigned short f2bf(float x) {
    unsigned int u = __float_as_uint(x);
    return (unsigned short)((u + 0x7fffu + ((u >> 16) & 1u)) >> 16);
}
__device__ __forceinline__ float bflo(unsigned int v) { return __uint_as_float(v << 16); }
__device__ __forceinline__ float bfhi(unsigned int v) { return __uint_as_float(v & 0xFFFF0000u); }
__device__ __forceinline__ unsigned int pack2(float a, float b) {
    return (unsigned int)f2bf(a) | ((unsigned int)f2bf(b) << 16);
}
__device__ __forceinline__ bf16x8 pack8(float4 a, float4 b) {
    union { unsigned short u[8]; bf16x8 v; } p;
    p.u[0] = f2bf(a.x); p.u[1] = f2bf(a.y); p.u[2] = f2bf(a.z); p.u[3] = f2bf(a.w);
    p.u[4] = f2bf(b.x); p.u[5] = f2bf(b.y); p.u[6] = f2bf(b.z); p.u[7] = f2bf(b.w);
    return p.v;
}

// Block-wide sum of (a,b). blockDim.x == 256.
__device__ __forceinline__ float2 block_reduce_sum2(float a, float b) {
    #pragma unroll
    for (int off = 1; off < 64; off <<= 1) {
        a += __shfl_xor(a, off, 64);
        b += __shfl_xor(b, off, 64);
    }
    __shared__ float lds[8];
    const int t = threadIdx.x;
    if ((t & 63) == 0) { lds[2 * (t >> 6)] = a; lds[2 * (t >> 6) + 1] = b; }
    __syncthreads();
    a = lds[0] + lds[2] + lds[4] + lds[6];
    b = lds[1] + lds[3] + lds[5] + lds[7];
    return make_float2(a, b);
}

// Packed activation layouts (bf16): h1p [n][4icq][64y][64x][4c]; LDS h2s [8icq][32y][32x][4c],
// h3s [16icq][16y][16x][4c]; h4 standard [n][128co][64px] (feeds FC1 GEMM).
// Conv GEMM k-order: k = icq*16 + row*8 + tx*4 + c  -> one 16B load per lane K-octet.
// wk: wk2 at 0 (32x64), wk3 at 2048 (64x128), wk4 at 10240 (128x256).

// ---------------- K1: conv1(3->16) + IN + lrelu -> packed bf16 (VALU) ------------
// Blocks 0..41 additionally reorder conv weights into wk (wprep folded in; k234
// launches after k1 completes, so ordering is safe). grid 256, 1024 thr.
__global__ __launch_bounds__(1024, 1) void k1_conv_in(const float* __restrict__ x,
                                                      const float* __restrict__ w1,
                                                      const float* __restrict__ w2,
                                                      const float* __restrict__ w3,
                                                      const float* __restrict__ w4,
                                                      unsigned short* __restrict__ h1,
                                                      unsigned short* __restrict__ wk) {
    const int n = blockIdx.x;
    const int t = threadIdx.x;
    if (n < 42) {   // folded wprep
        const int g = n * 1024 + t;
        if (g < 2048) {
            const int co = g >> 6, k = g & 63;
            const int ic = (k >> 4) * 4 + (k & 3), row = (k >> 3) & 1, tx = (k >> 2) & 1;
            wk[g] = f2bf(w2[co * 144 + ic * 4 + row * 2 + tx]);
        } else if (g < 10240) {
            const int e = g - 2048, co = e >> 7, k = e & 127;
            const int ic = (k >> 4) * 4 + (k & 3), row = (k >> 3) & 1, tx = (k >> 2) & 1;
            wk[g] = f2bf(w3[co * 128 + ic * 4 + row * 2 + tx]);
        } else if (g < 43008) {
            const int e = g - 10240, co = e >> 8, k = e & 255;
            const int ic = (k >> 4) * 4 + (k & 3), row = (k >> 3) & 1, tx = (k >> 2) & 1;
            wk[g] = f2bf(w4[co * 256 + ic * 4 + row * 2 + tx]);
        }
    }
    __shared__ float red[16][16][2];
    __shared__ float msc[16][2];
    const float* xn = x + (size_t)n * 49152;
    float acc[16][4];
    #pragma unroll
    for (int j = 0; j < 16; ++j)
        #pragma unroll
        for (int q = 0; q < 4; ++q) acc[j][q] = 0.f;
    #pragma unroll 1
    for (int ic = 0; ic < 3; ++ic) {
        const float* p = xn + ic * 16384;
        float2 v0[4], v1[4];
        #pragma unroll
        for (int q = 0; q < 4; ++q) {
            const int idx = t + 1024 * q;
            const int oy = idx >> 6, ox = idx & 63;
            v0[q] = ((const float2*)(p + (2 * oy) * 128))[ox];
            v1[q] = ((const float2*)(p + (2 * oy + 1) * 128))[ox];
        }
        #pragma unroll
        for (int j = 0; j < 16; ++j) {
            const float4 wv = *(const float4*)(w1 + j * 12 + ic * 4);  // uniform -> SGPR
            #pragma unroll
            for (int q = 0; q < 4; ++q)
                acc[j][q] += v0[q].x * wv.x + v0[q].y * wv.y + v1[q].x * wv.z + v1[q].y * wv.w;
        }
    }
    const int w = t >> 6, l = t & 63;
    #pragma unroll
    for (int j = 0; j < 16; ++j) {
        float s1 = acc[j][0] + acc[j][1] + acc[j][2] + acc[j][3];
        float s2 = acc[j][0] * acc[j][0] + acc[j][1] * acc[j][1] +
                   acc[j][2] * acc[j][2] + acc[j][3] * acc[j][3];
        #pragma unroll
        for (int off = 1; off < 64; off <<= 1) {
            s1 += __shfl_xor(s1, off, 64);
            s2 += __shfl_xor(s2, off, 64);
        }
        if (l == 0) { red[w][j][0] = s1; red[w][j][1] = s2; }
    }
    __syncthreads();
    if (t < 16) {
        float s1 = 0.f, s2 = 0.f;
        #pragma unroll
        for (int ww = 0; ww < 16; ++ww) { s1 += red[ww][t][0]; s2 += red[ww][t][1]; }
        const float mean = s1 * (1.f / 4096.f);
        const float var = s2 * (1.f / 4096.f) - mean * mean;
        msc[t][0] = mean; msc[t][1] = rsqrtf(var + EPSI);
    }
    __syncthreads();
    unsigned short* on = h1 + (size_t)n * 65536;
    #pragma unroll
    for (int q = 0; q < 4; ++q) {
        const int px = t + 1024 * q;
        #pragma unroll
        for (int q4 = 0; q4 < 4; ++q4) {
            const float n0 = lrelu((acc[4 * q4 + 0][q] - msc[4 * q4 + 0][0]) * msc[4 * q4 + 0][1]);
            const float n1 = lrelu((acc[4 * q4 + 1][q] - msc[4 * q4 + 1][0]) * msc[4 * q4 + 1][1]);
            const float n2 = lrelu((acc[4 * q4 + 2][q] - msc[4 * q4 + 2][0]) * msc[4 * q4 + 2][1]);
            const float n3 = lrelu((acc[4 * q4 + 3][q] - msc[4 * q4 + 3][0]) * msc[4 * q4 + 3][1]);
            uint2 u; u.x = pack2(n0, n1); u.y = pack2(n2, n3);
            *(uint2*)(on + ((size_t)q4 * 4096 + px) * 4) = u;
        }
    }
}

// ---------------- K234: conv2+conv3+conv4 fused, per-sample block ----------------
// 1024 thr (16 waves), 1 block/CU. h2 (64KB) and h3 (32KB) live in LDS only.
__global__ __launch_bounds__(1024, 1) void k234(const unsigned short* __restrict__ h1,
                                                const unsigned short* __restrict__ wk,
                                                unsigned short* __restrict__ h4) {
    const int n = blockIdx.x;
    const int t = threadIdx.x;
    const int w = t >> 6, l = t & 63;
    __shared__ unsigned short h2s[32768];   // 64KB packed [8icq][32y][32x][4c]
    __shared__ unsigned short h3s[16384];   // 32KB packed [16icq][16y][16x][4c]
    __shared__ float ps[4][64][32];         // 32KB phase-C partials
    __shared__ float red[16][64][2];        // 8KB
    __shared__ float msc[64][2];
    const unsigned short* h1n = h1 + (size_t)n * 65536;

    // ======== Phase A: conv2 [32co x 64K x 1024px] -> h2s ========
    {
        const unsigned short* wk2 = wk;
        bf16x8 af[2][2];
        #pragma unroll
        for (int cf = 0; cf < 2; ++cf)
            #pragma unroll
            for (int ks = 0; ks < 2; ++ks)
                af[cf][ks] = *(const bf16x8*)(wk2 + (cf * 16 + (l & 15)) * 64 + ks * 32 + (l >> 4) * 8);
        f32x4 acc[4][2];
        const f32x4 z = {0.f, 0.f, 0.f, 0.f};
        #pragma unroll
        for (int pg = 0; pg < 4; ++pg) { acc[pg][0] = z; acc[pg][1] = z; }
        const int row = (l >> 4) & 1, icq0 = (l >> 4) >> 1;
        #pragma unroll
        for (int pg = 0; pg < 4; ++pg) {
            const int oy = 2 * w + (pg >> 1);
            const int ox = (pg & 1) * 16 + (l & 15);
            #pragma unroll
            for (int ks = 0; ks < 2; ++ks) {
                const bf16x8 bv = *(const bf16x8*)(h1n + (ks * 2 + icq0) * 16384 + (2 * oy + row) * 256 + ox * 8);
                acc[pg][0] = __builtin_amdgcn_mfma_f32_16x16x32_bf16(af[0][ks], bv, acc[pg][0], 0, 0, 0);
                acc[pg][1] = __builtin_amdgcn_mfma_f32_16x16x32_bf16(af[1][ks], bv, acc[pg][1], 0, 0, 0);
            }
        }
        #pragma unroll
        for (int cf = 0; cf < 2; ++cf) {
            #pragma unroll
            for (int r = 0; r < 4; ++r) {
                float s1 = acc[0][cf][r] + acc[1][cf][r] + acc[2][cf][r] + acc[3][cf][r];
                float s2 = acc[0][cf][r] * acc[0][cf][r] + acc[1][cf][r] * acc[1][cf][r] +
                           acc[2][cf][r] * acc[2][cf][r] + acc[3][cf][r] * acc[3][cf][r];
                #pragma unroll
                for (int off = 1; off < 16; off <<= 1) {
                    s1 += __shfl_xor(s1, off, 64);
                    s2 += __shfl_xor(s2, off, 64);
                }
                if ((l & 15) == 0) {
                    red[w][cf * 16 + (l >> 4) * 4 + r][0] = s1;
                    red[w][cf * 16 + (l >> 4) * 4 + r][1] = s2;
                }
            }
        }
        __syncthreads();
        if (t < 32) {
            float s1 = 0.f, s2 = 0.f;
            #pragma unroll
            for (int ww = 0; ww < 16; ++ww) { s1 += red[ww][t][0]; s2 += red[ww][t][1]; }
            const float mean = s1 * (1.f / 1024.f);
            const float var = s2 * (1.f / 1024.f) - mean * mean;
            msc[t][0] = mean; msc[t][1] = rsqrtf(var + EPSI);
        }
        __syncthreads();
        #pragma unroll
        for (int pg = 0; pg < 4; ++pg) {
            const int px = w * 64 + pg * 16 + (l & 15);
            #pragma unroll
            for (int cf = 0; cf < 2; ++cf) {
                const int co0 = cf * 16 + (l >> 4) * 4;
                float v[4];
                #pragma unroll
                for (int r = 0; r < 4; ++r)
                    v[r] = lrelu((acc[pg][cf][r] - msc[co0 + r][0]) * msc[co0 + r][1]);
                uint2 u; u.x = pack2(v[0], v[1]); u.y = pack2(v[2], v[3]);
                *(uint2*)(&h2s[((cf * 4 + (l >> 4)) * 1024 + px) * 4]) = u;
            }
        }
    }
    __syncthreads();

    // ======== Phase B: conv3 [64co x 128K x 256px], h2s -> h3s ========
    {
        const unsigned short* wk3 = wk + 2048;
        f32x4 acc[4];
        const f32x4 z = {0.f, 0.f, 0.f, 0.f};
        #pragma unroll
        for (int cf = 0; cf < 4; ++cf) acc[cf] = z;
        const int row = (l >> 4) & 1, icq0 = (l >> 4) >> 1;
        #pragma unroll
        for (int ks = 0; ks < 4; ++ks) {
            const bf16x8 bv = *(const bf16x8*)(&h2s[(ks * 2 + icq0) * 4096 + (2 * w + row) * 128 + (l & 15) * 8]);
            #pragma unroll
            for (int cf = 0; cf < 4; ++cf) {
                const bf16x8 af = *(const bf16x8*)(wk3 + (cf * 16 + (l & 15)) * 128 + ks * 32 + (l >> 4) * 8);
                acc[cf] = __builtin_amdgcn_mfma_f32_16x16x32_bf16(af, bv, acc[cf], 0, 0, 0);
            }
        }
        #pragma unroll
        for (int cf = 0; cf < 4; ++cf) {
            #pragma unroll
            for (int r = 0; r < 4; ++r) {
                float s1 = acc[cf][r], s2 = acc[cf][r] * acc[cf][r];
                #pragma unroll
                for (int off = 1; off < 16; off <<= 1) {
                    s1 += __shfl_xor(s1, off, 64);
                    s2 += __shfl_xor(s2, off, 64);
                }
                if ((l & 15) == 0) {
                    red[w][cf * 16 + (l >> 4) * 4 + r][0] = s1;
                    red[w][cf * 16 + (l >> 4) * 4 + r][1] = s2;
                }
            }
        }
        __syncthreads();
        if (t < 64) {
            float s1 = 0.f, s2 = 0.f;
            #pragma unroll
            for (int ww = 0; ww < 16; ++ww) { s1 += red[ww][t][0]; s2 += red[ww][t][1]; }
            const float mean = s1 * (1.f / 256.f);
            const float var = s2 * (1.f / 256.f) - mean * mean;
            msc[t][0] = mean; msc[t][1] = rsqrtf(var + EPSI);
        }
        __syncthreads();
        const int px = w * 16 + (l & 15);
        #pragma unroll
        for (int cf = 0; cf < 4; ++cf) {
            const int co0 = cf * 16 + (l >> 4) * 4;
            float v[4];
            #pragma unroll
            for (int r = 0; r < 4; ++r)
                v[r] = lrelu((acc[cf][r] - msc[co0 + r][0]) * msc[co0 + r][1]);
            uint2 u; u.x = pack2(v[0], v[1]); u.y = pack2(v[2], v[3]);
            *(uint2*)(&h3s[((cf * 4 + (l >> 4)) * 256 + px) * 4]) = u;
        }
    }
    __syncthreads();

    // ======== Phase C: conv4 [128co x 256K x 64px], h3s -> h4 (waves 0-7) ========
    {
        const unsigned short* wk4 = wk + 10240;
        const int cfp = w & 3, khalf = (w >> 2) & 1;
        f32x4 acc[4][2];
        const f32x4 z = {0.f, 0.f, 0.f, 0.f};
        #pragma unroll
        for (int pg = 0; pg < 4; ++pg) { acc[pg][0] = z; acc[pg][1] = z; }
        const int row = (l >> 4) & 1, icq0 = (l >> 4) >> 1;
        const int oyb = (l & 15) >> 3, ox = l & 7;
        if (w < 8) {
            #pragma unroll
            for (int ksl = 0; ksl < 4; ++ksl) {
                const int ks = khalf * 4 + ksl;
                bf16x8 af0 = *(const bf16x8*)(wk4 + ((cfp * 2 + 0) * 16 + (l & 15)) * 256 + ks * 32 + (l >> 4) * 8);
                bf16x8 af1 = *(const bf16x8*)(wk4 + ((cfp * 2 + 1) * 16 + (l & 15)) * 256 + ks * 32 + (l >> 4) * 8);
                #pragma unroll
                for (int pg = 0; pg < 4; ++pg) {
                    const int oy = pg * 2 + oyb;
                    const bf16x8 bv = *(const bf16x8*)(&h3s[(ks * 2 + icq0) * 1024 + (2 * oy + row) * 64 + ox * 8]);
                    acc[pg][0] = __builtin_amdgcn_mfma_f32_16x16x32_bf16(af0, bv, acc[pg][0], 0, 0, 0);
                    acc[pg][1] = __builtin_amdgcn_mfma_f32_16x16x32_bf16(af1, bv, acc[pg][1], 0, 0, 0);
                }
            }
        }
        if (w < 4) {   // khalf == 0
            #pragma unroll
            for (int pg = 0; pg < 4; ++pg)
                #pragma unroll
                for (int cfi = 0; cfi < 2; ++cfi)
                    #pragma unroll
                    for (int r = 0; r < 4; ++r)
                        ps[cfp][l][pg * 8 + cfi * 4 + r] = acc[pg][cfi][r];
        }
        __syncthreads();
        if (w >= 4 && w < 8) {   // khalf == 1: combine + IN + store
            unsigned short* on = h4 + (size_t)n * 8192;
            #pragma unroll
            for (int cfi = 0; cfi < 2; ++cfi) {
                #pragma unroll
                for (int r = 0; r < 4; ++r) {
                    float v[4];
                    #pragma unroll
                    for (int pg = 0; pg < 4; ++pg)
                        v[pg] = acc[pg][cfi][r] + ps[cfp][l][pg * 8 + cfi * 4 + r];
                    float s1 = v[0] + v[1] + v[2] + v[3];
                    float s2 = v[0] * v[0] + v[1] * v[1] + v[2] * v[2] + v[3] * v[3];
                    #pragma unroll
                    for (int off = 1; off < 16; off <<= 1) {
                        s1 += __shfl_xor(s1, off, 64);
                        s2 += __shfl_xor(s2, off, 64);
                    }
                    const float mean = s1 * (1.f / 64.f);
                    const float var = s2 * (1.f / 64.f) - mean * mean;
                    const float sc = rsqrtf(var + EPSI);
                    const int co = (cfp * 2 + cfi) * 16 + (l >> 4) * 4 + r;
                    #pragma unroll
                    for (int pg = 0; pg < 4; ++pg)
                        on[co * 64 + pg * 16 + (l & 15)] = f2bf(lrelu((v[pg] - mean) * sc));
                }
            }
        }
    }
}

// ---------------- K5: FC1 bf16 MFMA split-K GEMM, SK=32, bf16 partials -----------
// C[256,1024] = A[256,8192](bf16) x W[1024,8192]^T(fp32->bf16 on the fly).
// BM=BN=128, BK=64, SK=32 (K-chunk 256): grid = 16 tiles x 32 sk = 512 blocks
// (2 blocks/CU on ALL 256 CUs; R14 had 256 blocks = half chip). Cp stored bf16.
__global__ __launch_bounds__(256, 2) void k5_fc1(const unsigned short* __restrict__ A,
                                                 const float* __restrict__ Wf,
                                                 unsigned short* __restrict__ Cp) {
    __shared__ unsigned short As[128 * 72];
    __shared__ unsigned short Bs[128 * 72];
    const int t = threadIdx.x;
    const int sk = blockIdx.x >> 4;          // 0..31
    const int tile = blockIdx.x & 15;
    const int mt = tile >> 3, nt = tile & 7;
    const int m0 = mt * 128, n0 = nt * 128;
    const int w = t >> 6, l = t & 63;
    const int wm = (w >> 1) * 64, wn = (w & 1) * 64;
    const int lr16 = l & 15, lk8 = (l >> 4) * 8;
    const int srow = t >> 3, scol = (t & 7) * 8;
    f32x4 acc[4][4];
    const f32x4 z = {0.f, 0.f, 0.f, 0.f};
    #pragma unroll
    for (int f = 0; f < 4; ++f)
        #pragma unroll
        for (int g = 0; g < 4; ++g) acc[f][g] = z;
    const int kbeg = sk * 256;
    #pragma unroll 1
    for (int kt = 0; kt < 4; ++kt) {
        const int kc = kbeg + kt * 64;
        bf16x8 av[4], bv[4];
        #pragma unroll
        for (int i = 0; i < 4; ++i) {
            av[i] = *(const bf16x8*)(A + (size_t)(m0 + srow + 32 * i) * 8192 + kc + scol);
            const float4 w0 = *(const float4*)(Wf + (size_t)(n0 + srow + 32 * i) * 8192 + kc + scol);
            const float4 w1 = *(const float4*)(Wf + (size_t)(n0 + srow + 32 * i) * 8192 + kc + scol + 4);
            bv[i] = pack8(w0, w1);
        }
        __syncthreads();
        #pragma unroll
        for (int i = 0; i < 4; ++i) {
            *(bf16x8*)&As[(srow + 32 * i) * 72 + scol] = av[i];
            *(bf16x8*)&Bs[(srow + 32 * i) * 72 + scol] = bv[i];
        }
        __syncthreads();
        #pragma unroll
        for (int ks = 0; ks < 2; ++ks) {
            bf16x8 af[4], bfr[4];
            #pragma unroll
            for (int f = 0; f < 4; ++f)
                af[f] = *(const bf16x8*)&As[(wm + f * 16 + lr16) * 72 + ks * 32 + lk8];
            #pragma unroll
            for (int g = 0; g < 4; ++g)
                bfr[g] = *(const bf16x8*)&Bs[(wn + g * 16 + lr16) * 72 + ks * 32 + lk8];
            #pragma unroll
            for (int f = 0; f < 4; ++f)
                #pragma unroll
                for (int g = 0; g < 4; ++g)
                    acc[f][g] = __builtin_amdgcn_mfma_f32_16x16x32_bf16(af[f], bfr[g], acc[f][g], 0, 0, 0);
        }
    }
    const int orow = (l >> 4) * 4, ocol = l & 15;
    #pragma unroll
    for (int f = 0; f < 4; ++f) {
        #pragma unroll
        for (int g = 0; g < 4; ++g) {
            #pragma unroll
            for (int j = 0; j < 4; ++j) {
                const int m = m0 + wm + f * 16 + orow + j;
                const int nn = n0 + wn + g * 16 + ocol;
                Cp[((size_t)sk * 256 + m) * 1024 + nn] = f2bf(acc[f][g][j]);
            }
        }
    }
}

// ---------------- K6: fused split-K reduce + bias + lrelu + FC2 ------------------
// Thread t owns nn = 4t..4t+3: one uint2 (4 bf16) load per sk partial.
__global__ __launch_bounds__(256) void k6_fc2(const unsigned short* __restrict__ Cp,
                                              const float* __restrict__ bias,
                                              const float* __restrict__ w,
                                              const float* __restrict__ b,
                                              float* __restrict__ out) {
    const int n = blockIdx.x, t = threadIdx.x;
    const int nn0 = t * 4;
    float s0 = 0.f, s1 = 0.f, s2 = 0.f, s3 = 0.f;
    #pragma unroll
    for (int sk = 0; sk < 32; ++sk) {
        const uint2 u = *(const uint2*)(Cp + ((size_t)sk * 256 + n) * 1024 + nn0);
        s0 += bflo(u.x); s1 += bfhi(u.x); s2 += bflo(u.y); s3 += bfhi(u.y);
    }
    const float4 bi = *(const float4*)(bias + nn0);
    const float4 wv = *(const float4*)(w + nn0);
    float part = lrelu(s0 + bi.x) * wv.x + lrelu(s1 + bi.y) * wv.y +
                 lrelu(s2 + bi.z) * wv.z + lrelu(s3 + bi.w) * wv.w;
    const float2 red = block_reduce_sum2(part, 0.f);
    if (t == 0) out[n] = red.x + b[0];
}

extern "C" void kernel_launch(void* const* d_in, const int* in_sizes, int n_in,
                              void* d_out, int out_size, void* d_ws, size_t ws_size,
                              hipStream_t stream) {
    (void)in_sizes; (void)n_in; (void)out_size; (void)ws_size;
    const float* x    = (const float*)d_in[0];
    // labels (d_in[1]) and conv biases (d_in[3,5,7,9]) cancel exactly under InstanceNorm
    const float* w1   = (const float*)d_in[2];
    const float* w2   = (const float*)d_in[4];
    const float* w3   = (const float*)d_in[6];
    const float* w4   = (const float*)d_in[8];
    const float* fcw1 = (const float*)d_in[10];
    const float* fcb1 = (const float*)d_in[11];
    const float* fcw2 = (const float*)d_in[12];
    const float* fcb2 = (const float*)d_in[13];
    float* out = (float*)d_out;
    float* bufA = (float*)d_ws;                    // 16.7M floats
    float* bufB = bufA + 16777216;                 //  8.4M floats
    unsigned short* h1 = (unsigned short*)bufA;    // packed, 16.7M shorts (33.5 MB)
    unsigned short* h4 = (unsigned short*)bufB;    // standard, 2.1M shorts
    unsigned short* wk = (unsigned short*)bufB + 12582912;  // 43008 shorts, clear of h4
    unsigned short* Cp = (unsigned short*)bufA;    // 32*256*1024 bf16 = 16.8 MB (h1 dead at k5)
    k1_conv_in<<<256, 1024, 0, stream>>>(x, w1, w2, w3, w4, h1, wk);
    k234<<<256, 1024, 0, stream>>>(h1, wk, h4);
    k5_fc1<<<512, 256, 0, stream>>>(h4, fcw1, Cp);
    k6_fc2<<<256, 256, 0, stream>>>(Cp, fcb1, fcw2, fcb2, out);
}

// Round 16
// 74.771 us; speedup vs baseline: 2.6892x; 1.0233x over previous
//
#include <hip/hip_runtime.h>

#define EPSI 1e-5f

typedef __attribute__((ext_vector_type(8))) short bf16x8;
typedef __attribute__((ext_vector_type(4))) float f32x4;

__device__ __forceinline__ float lrelu(float x) { return x > 0.f ? x : 0.01f * x; }

// float -> bf16 bits, round-to-nearest-even (header-free)
__device__ __forceinline__ unsigned short f2bf(float x) {
    unsigned int u = __float_as_uint(x);
    return (unsigned short)((u + 0x7fffu + ((u >> 16) & 1u)) >> 16);
}
__device__ __forceinline__ float bflo(unsigned int v) { return __uint_as_float(v << 16); }
__device__ __forceinline__ float bfhi(unsigned int v) { return __uint_as_float(v & 0xFFFF0000u); }
__device__ __forceinline__ unsigned int pack2(float a, float b) {
    return (unsigned int)f2bf(a) | ((unsigned int)f2bf(b) << 16);
}
__device__ __forceinline__ bf16x8 pack8(float4 a, float4 b) {
    union { unsigned short u[8]; bf16x8 v; } p;
    p.u[0] = f2bf(a.x); p.u[1] = f2bf(a.y); p.u[2] = f2bf(a.z); p.u[3] = f2bf(a.w);
    p.u[4] = f2bf(b.x); p.u[5] = f2bf(b.y); p.u[6] = f2bf(b.z); p.u[7] = f2bf(b.w);
    return p.v;
}

// Block-wide sum of (a,b). blockDim.x == 256.
__device__ __forceinline__ float2 block_reduce_sum2(float a, float b) {
    #pragma unroll
    for (int off = 1; off < 64; off <<= 1) {
        a += __shfl_xor(a, off, 64);
        b += __shfl_xor(b, off, 64);
    }
    __shared__ float lds[8];
    const int t = threadIdx.x;
    if ((t & 63) == 0) { lds[2 * (t >> 6)] = a; lds[2 * (t >> 6) + 1] = b; }
    __syncthreads();
    a = lds[0] + lds[2] + lds[4] + lds[6];
    b = lds[1] + lds[3] + lds[5] + lds[7];
    return make_float2(a, b);
}

// Packed activation layouts (bf16), all in LDS inside k1234:
//   h1s [4icq][64y][64x][4c] = 128KB;  h2s [8icq][32y][32x][4c] = 64KB (aliases h1s);
//   h3s [16icq][16y][16x][4c] = 32KB;  ps = 32KB (aliases h2s).
// h4 global standard [n][128co][64px] (feeds FC1 GEMM).
// Conv GEMM k-order: k = icq*16 + row*8 + tx*4 + c  -> one 16B load per lane K-octet.
// wk: wk2 at 0 (32x64), wk3 at 2048 (64x128), wk4 at 10240 (128x256).

// ---------------- WPREP: reorder conv weights to bf16 wk[co][k] ------------------
// Separate kernel: k1234 consumes wk in-kernel, so folding this in would be a
// cross-block ordering race (G16).
__global__ __launch_bounds__(1024) void wprep(const float* __restrict__ w2,
                                              const float* __restrict__ w3,
                                              const float* __restrict__ w4,
                                              unsigned short* __restrict__ wk) {
    const int g = blockIdx.x * 1024 + threadIdx.x;
    if (g < 2048) {
        const int co = g >> 6, k = g & 63;
        const int ic = (k >> 4) * 4 + (k & 3), row = (k >> 3) & 1, tx = (k >> 2) & 1;
        wk[g] = f2bf(w2[co * 144 + ic * 4 + row * 2 + tx]);
    } else if (g < 10240) {
        const int e = g - 2048, co = e >> 7, k = e & 127;
        const int ic = (k >> 4) * 4 + (k & 3), row = (k >> 3) & 1, tx = (k >> 2) & 1;
        wk[g] = f2bf(w3[co * 128 + ic * 4 + row * 2 + tx]);
    } else if (g < 43008) {
        const int e = g - 10240, co = e >> 8, k = e & 255;
        const int ic = (k >> 4) * 4 + (k & 3), row = (k >> 3) & 1, tx = (k >> 2) & 1;
        wk[g] = f2bf(w4[co * 256 + ic * 4 + row * 2 + tx]);
    }
}

// ---------------- K1234: conv1+conv2+conv3+conv4 fully fused, per-sample ---------
// 1024 thr (16 waves), 1 block/CU. h1 never touches HBM (was a 67MB round trip).
// LDS aliasing is safe: each region is fully consumed before its successor's
// writes (separated by the IN-reduce barriers of each phase).
__global__ __launch_bounds__(1024, 1) void k1234(const float* __restrict__ x,
                                                 const float* __restrict__ w1,
                                                 const unsigned short* __restrict__ wk,
                                                 unsigned short* __restrict__ h4) {
    const int n = blockIdx.x;
    const int t = threadIdx.x;
    const int w = t >> 6, l = t & 63;
    __shared__ __align__(16) unsigned char smem[131072];   // 128KB phase-aliased
    __shared__ float red[16][64][2];                       // 8KB
    __shared__ float msc[64][2];
    unsigned short* h1s = (unsigned short*)smem;           // [0,128K) phase 0 -> A
    unsigned short* h2s = (unsigned short*)smem;           // [0,64K)  phase A -> B
    unsigned short* h3s = (unsigned short*)(smem + 65536); // [64K,96K) phase B -> C
    float* ps = (float*)smem;                              // [0,32K)  phase C partials

    // ======== Phase 0: conv1 (VALU) + IN + lrelu -> h1s (LDS) ========
    {
        const float* xn = x + (size_t)n * 49152;
        float acc[16][4];
        #pragma unroll
        for (int j = 0; j < 16; ++j)
            #pragma unroll
            for (int q = 0; q < 4; ++q) acc[j][q] = 0.f;
        #pragma unroll 1
        for (int ic = 0; ic < 3; ++ic) {
            const float* p = xn + ic * 16384;
            float2 v0[4], v1[4];
            #pragma unroll
            for (int q = 0; q < 4; ++q) {
                const int idx = t + 1024 * q;
                const int oy = idx >> 6, ox = idx & 63;
                v0[q] = ((const float2*)(p + (2 * oy) * 128))[ox];
                v1[q] = ((const float2*)(p + (2 * oy + 1) * 128))[ox];
            }
            #pragma unroll
            for (int j = 0; j < 16; ++j) {
                const float4 wv = *(const float4*)(w1 + j * 12 + ic * 4);  // uniform -> SGPR
                #pragma unroll
                for (int q = 0; q < 4; ++q)
                    acc[j][q] += v0[q].x * wv.x + v0[q].y * wv.y + v1[q].x * wv.z + v1[q].y * wv.w;
            }
        }
        #pragma unroll
        for (int j = 0; j < 16; ++j) {
            float s1 = acc[j][0] + acc[j][1] + acc[j][2] + acc[j][3];
            float s2 = acc[j][0] * acc[j][0] + acc[j][1] * acc[j][1] +
                       acc[j][2] * acc[j][2] + acc[j][3] * acc[j][3];
            #pragma unroll
            for (int off = 1; off < 64; off <<= 1) {
                s1 += __shfl_xor(s1, off, 64);
                s2 += __shfl_xor(s2, off, 64);
            }
            if (l == 0) { red[w][j][0] = s1; red[w][j][1] = s2; }
        }
        __syncthreads();
        if (t < 16) {
            float s1 = 0.f, s2 = 0.f;
            #pragma unroll
            for (int ww = 0; ww < 16; ++ww) { s1 += red[ww][t][0]; s2 += red[ww][t][1]; }
            const float mean = s1 * (1.f / 4096.f);
            const float var = s2 * (1.f / 4096.f) - mean * mean;
            msc[t][0] = mean; msc[t][1] = rsqrtf(var + EPSI);
        }
        __syncthreads();
        #pragma unroll
        for (int q = 0; q < 4; ++q) {
            const int px = t + 1024 * q;
            #pragma unroll
            for (int q4 = 0; q4 < 4; ++q4) {
                const float n0 = lrelu((acc[4 * q4 + 0][q] - msc[4 * q4 + 0][0]) * msc[4 * q4 + 0][1]);
                const float n1 = lrelu((acc[4 * q4 + 1][q] - msc[4 * q4 + 1][0]) * msc[4 * q4 + 1][1]);
                const float n2 = lrelu((acc[4 * q4 + 2][q] - msc[4 * q4 + 2][0]) * msc[4 * q4 + 2][1]);
                const float n3 = lrelu((acc[4 * q4 + 3][q] - msc[4 * q4 + 3][0]) * msc[4 * q4 + 3][1]);
                uint2 u; u.x = pack2(n0, n1); u.y = pack2(n2, n3);
                *(uint2*)(&h1s[((size_t)q4 * 4096 + px) * 4]) = u;
            }
        }
    }
    __syncthreads();

    // ======== Phase A: conv2 [32co x 64K x 1024px], h1s -> h2s ========
    {
        const unsigned short* wk2 = wk;
        bf16x8 af[2][2];
        #pragma unroll
        for (int cf = 0; cf < 2; ++cf)
            #pragma unroll
            for (int ks = 0; ks < 2; ++ks)
                af[cf][ks] = *(const bf16x8*)(wk2 + (cf * 16 + (l & 15)) * 64 + ks * 32 + (l >> 4) * 8);
        f32x4 acc[4][2];
        const f32x4 z = {0.f, 0.f, 0.f, 0.f};
        #pragma unroll
        for (int pg = 0; pg < 4; ++pg) { acc[pg][0] = z; acc[pg][1] = z; }
        const int row = (l >> 4) & 1, icq0 = (l >> 4) >> 1;
        #pragma unroll
        for (int pg = 0; pg < 4; ++pg) {
            const int oy = 2 * w + (pg >> 1);
            const int ox = (pg & 1) * 16 + (l & 15);
            #pragma unroll
            for (int ks = 0; ks < 2; ++ks) {
                const bf16x8 bv = *(const bf16x8*)(&h1s[(ks * 2 + icq0) * 16384 + (2 * oy + row) * 256 + ox * 8]);
                acc[pg][0] = __builtin_amdgcn_mfma_f32_16x16x32_bf16(af[0][ks], bv, acc[pg][0], 0, 0, 0);
                acc[pg][1] = __builtin_amdgcn_mfma_f32_16x16x32_bf16(af[1][ks], bv, acc[pg][1], 0, 0, 0);
            }
        }
        #pragma unroll
        for (int cf = 0; cf < 2; ++cf) {
            #pragma unroll
            for (int r = 0; r < 4; ++r) {
                float s1 = acc[0][cf][r] + acc[1][cf][r] + acc[2][cf][r] + acc[3][cf][r];
                float s2 = acc[0][cf][r] * acc[0][cf][r] + acc[1][cf][r] * acc[1][cf][r] +
                           acc[2][cf][r] * acc[2][cf][r] + acc[3][cf][r] * acc[3][cf][r];
                #pragma unroll
                for (int off = 1; off < 16; off <<= 1) {
                    s1 += __shfl_xor(s1, off, 64);
                    s2 += __shfl_xor(s2, off, 64);
                }
                if ((l & 15) == 0) {
                    red[w][cf * 16 + (l >> 4) * 4 + r][0] = s1;
                    red[w][cf * 16 + (l >> 4) * 4 + r][1] = s2;
                }
            }
        }
        __syncthreads();   // all h1s reads complete here -> h2s may alias h1s
        if (t < 32) {
            float s1 = 0.f, s2 = 0.f;
            #pragma unroll
            for (int ww = 0; ww < 16; ++ww) { s1 += red[ww][t][0]; s2 += red[ww][t][1]; }
            const float mean = s1 * (1.f / 1024.f);
            const float var = s2 * (1.f / 1024.f) - mean * mean;
            msc[t][0] = mean; msc[t][1] = rsqrtf(var + EPSI);
        }
        __syncthreads();
        #pragma unroll
        for (int pg = 0; pg < 4; ++pg) {
            const int px = w * 64 + pg * 16 + (l & 15);
            #pragma unroll
            for (int cf = 0; cf < 2; ++cf) {
                const int co0 = cf * 16 + (l >> 4) * 4;
                float v[4];
                #pragma unroll
                for (int r = 0; r < 4; ++r)
                    v[r] = lrelu((acc[pg][cf][r] - msc[co0 + r][0]) * msc[co0 + r][1]);
                uint2 u; u.x = pack2(v[0], v[1]); u.y = pack2(v[2], v[3]);
                *(uint2*)(&h2s[((cf * 4 + (l >> 4)) * 1024 + px) * 4]) = u;
            }
        }
    }
    __syncthreads();

    // ======== Phase B: conv3 [64co x 128K x 256px], h2s -> h3s ========
    {
        const unsigned short* wk3 = wk + 2048;
        f32x4 acc[4];
        const f32x4 z = {0.f, 0.f, 0.f, 0.f};
        #pragma unroll
        for (int cf = 0; cf < 4; ++cf) acc[cf] = z;
        const int row = (l >> 4) & 1, icq0 = (l >> 4) >> 1;
        #pragma unroll
        for (int ks = 0; ks < 4; ++ks) {
            const bf16x8 bv = *(const bf16x8*)(&h2s[(ks * 2 + icq0) * 4096 + (2 * w + row) * 128 + (l & 15) * 8]);
            #pragma unroll
            for (int cf = 0; cf < 4; ++cf) {
                const bf16x8 af = *(const bf16x8*)(wk3 + (cf * 16 + (l & 15)) * 128 + ks * 32 + (l >> 4) * 8);
                acc[cf] = __builtin_amdgcn_mfma_f32_16x16x32_bf16(af, bv, acc[cf], 0, 0, 0);
            }
        }
        #pragma unroll
        for (int cf = 0; cf < 4; ++cf) {
            #pragma unroll
            for (int r = 0; r < 4; ++r) {
                float s1 = acc[cf][r], s2 = acc[cf][r] * acc[cf][r];
                #pragma unroll
                for (int off = 1; off < 16; off <<= 1) {
                    s1 += __shfl_xor(s1, off, 64);
                    s2 += __shfl_xor(s2, off, 64);
                }
                if ((l & 15) == 0) {
                    red[w][cf * 16 + (l >> 4) * 4 + r][0] = s1;
                    red[w][cf * 16 + (l >> 4) * 4 + r][1] = s2;
                }
            }
        }
        __syncthreads();
        if (t < 64) {
            float s1 = 0.f, s2 = 0.f;
            #pragma unroll
            for (int ww = 0; ww < 16; ++ww) { s1 += red[ww][t][0]; s2 += red[ww][t][1]; }
            const float mean = s1 * (1.f / 256.f);
            const float var = s2 * (1.f / 256.f) - mean * mean;
            msc[t][0] = mean; msc[t][1] = rsqrtf(var + EPSI);
        }
        __syncthreads();
        const int px = w * 16 + (l & 15);
        #pragma unroll
        for (int cf = 0; cf < 4; ++cf) {
            const int co0 = cf * 16 + (l >> 4) * 4;
            float v[4];
            #pragma unroll
            for (int r = 0; r < 4; ++r)
                v[r] = lrelu((acc[cf][r] - msc[co0 + r][0]) * msc[co0 + r][1]);
            uint2 u; u.x = pack2(v[0], v[1]); u.y = pack2(v[2], v[3]);
            *(uint2*)(&h3s[((cf * 4 + (l >> 4)) * 256 + px) * 4]) = u;
        }
    }
    __syncthreads();

    // ======== Phase C: conv4 [128co x 256K x 64px], h3s -> h4 (waves 0-7) ========
    {
        const unsigned short* wk4 = wk + 10240;
        const int cfp = w & 3, khalf = (w >> 2) & 1;
        f32x4 acc[4][2];
        const f32x4 z = {0.f, 0.f, 0.f, 0.f};
        #pragma unroll
        for (int pg = 0; pg < 4; ++pg) { acc[pg][0] = z; acc[pg][1] = z; }
        const int row = (l >> 4) & 1, icq0 = (l >> 4) >> 1;
        const int oyb = (l & 15) >> 3, ox = l & 7;
        if (w < 8) {
            #pragma unroll
            for (int ksl = 0; ksl < 4; ++ksl) {
                const int ks = khalf * 4 + ksl;
                bf16x8 af0 = *(const bf16x8*)(wk4 + ((cfp * 2 + 0) * 16 + (l & 15)) * 256 + ks * 32 + (l >> 4) * 8);
                bf16x8 af1 = *(const bf16x8*)(wk4 + ((cfp * 2 + 1) * 16 + (l & 15)) * 256 + ks * 32 + (l >> 4) * 8);
                #pragma unroll
                for (int pg = 0; pg < 4; ++pg) {
                    const int oy = pg * 2 + oyb;
                    const bf16x8 bv = *(const bf16x8*)(&h3s[(ks * 2 + icq0) * 1024 + (2 * oy + row) * 64 + ox * 8]);
                    acc[pg][0] = __builtin_amdgcn_mfma_f32_16x16x32_bf16(af0, bv, acc[pg][0], 0, 0, 0);
                    acc[pg][1] = __builtin_amdgcn_mfma_f32_16x16x32_bf16(af1, bv, acc[pg][1], 0, 0, 0);
                }
            }
        }
        if (w < 4) {   // khalf == 0: stash partials (ps aliases dead h2s)
            #pragma unroll
            for (int pg = 0; pg < 4; ++pg)
                #pragma unroll
                for (int cfi = 0; cfi < 2; ++cfi)
                    #pragma unroll
                    for (int r = 0; r < 4; ++r)
                        ps[(cfp * 64 + l) * 32 + pg * 8 + cfi * 4 + r] = acc[pg][cfi][r];
        }
        __syncthreads();
        if (w >= 4 && w < 8) {   // khalf == 1: combine + IN + store
            unsigned short* on = h4 + (size_t)n * 8192;
            #pragma unroll
            for (int cfi = 0; cfi < 2; ++cfi) {
                #pragma unroll
                for (int r = 0; r < 4; ++r) {
                    float v[4];
                    #pragma unroll
                    for (int pg = 0; pg < 4; ++pg)
                        v[pg] = acc[pg][cfi][r] + ps[(cfp * 64 + l) * 32 + pg * 8 + cfi * 4 + r];
                    float s1 = v[0] + v[1] + v[2] + v[3];
                    float s2 = v[0] * v[0] + v[1] * v[1] + v[2] * v[2] + v[3] * v[3];
                    #pragma unroll
                    for (int off = 1; off < 16; off <<= 1) {
                        s1 += __shfl_xor(s1, off, 64);
                        s2 += __shfl_xor(s2, off, 64);
                    }
                    const float mean = s1 * (1.f / 64.f);
                    const float var = s2 * (1.f / 64.f) - mean * mean;
                    const float sc = rsqrtf(var + EPSI);
                    const int co = (cfp * 2 + cfi) * 16 + (l >> 4) * 4 + r;
                    #pragma unroll
                    for (int pg = 0; pg < 4; ++pg)
                        on[co * 64 + pg * 16 + (l & 15)] = f2bf(lrelu((v[pg] - mean) * sc));
                }
            }
        }
    }
}

// ---------------- K5: FC1 bf16 MFMA split-K GEMM, SK=32, bf16 partials -----------
// C[256,1024] = A[256,8192](bf16) x W[1024,8192]^T(fp32->bf16 on the fly).
// BM=BN=128, BK=64, SK=32: grid = 512 blocks (2/CU on all 256 CUs).
__global__ __launch_bounds__(256, 2) void k5_fc1(const unsigned short* __restrict__ A,
                                                 const float* __restrict__ Wf,
                                                 unsigned short* __restrict__ Cp) {
    __shared__ unsigned short As[128 * 72];
    __shared__ unsigned short Bs[128 * 72];
    const int t = threadIdx.x;
    const int sk = blockIdx.x >> 4;          // 0..31
    const int tile = blockIdx.x & 15;
    const int mt = tile >> 3, nt = tile & 7;
    const int m0 = mt * 128, n0 = nt * 128;
    const int w = t >> 6, l = t & 63;
    const int wm = (w >> 1) * 64, wn = (w & 1) * 64;
    const int lr16 = l & 15, lk8 = (l >> 4) * 8;
    const int srow = t >> 3, scol = (t & 7) * 8;
    f32x4 acc[4][4];
    const f32x4 z = {0.f, 0.f, 0.f, 0.f};
    #pragma unroll
    for (int f = 0; f < 4; ++f)
        #pragma unroll
        for (int g = 0; g < 4; ++g) acc[f][g] = z;
    const int kbeg = sk * 256;
    #pragma unroll 1
    for (int kt = 0; kt < 4; ++kt) {
        const int kc = kbeg + kt * 64;
        bf16x8 av[4], bv[4];
        #pragma unroll
        for (int i = 0; i < 4; ++i) {
            av[i] = *(const bf16x8*)(A + (size_t)(m0 + srow + 32 * i) * 8192 + kc + scol);
            const float4 w0 = *(const float4*)(Wf + (size_t)(n0 + srow + 32 * i) * 8192 + kc + scol);
            const float4 w1 = *(const float4*)(Wf + (size_t)(n0 + srow + 32 * i) * 8192 + kc + scol + 4);
            bv[i] = pack8(w0, w1);
        }
        __syncthreads();
        #pragma unroll
        for (int i = 0; i < 4; ++i) {
            *(bf16x8*)&As[(srow + 32 * i) * 72 + scol] = av[i];
            *(bf16x8*)&Bs[(srow + 32 * i) * 72 + scol] = bv[i];
        }
        __syncthreads();
        #pragma unroll
        for (int ks = 0; ks < 2; ++ks) {
            bf16x8 af[4], bfr[4];
            #pragma unroll
            for (int f = 0; f < 4; ++f)
                af[f] = *(const bf16x8*)&As[(wm + f * 16 + lr16) * 72 + ks * 32 + lk8];
            #pragma unroll
            for (int g = 0; g < 4; ++g)
                bfr[g] = *(const bf16x8*)&Bs[(wn + g * 16 + lr16) * 72 + ks * 32 + lk8];
            #pragma unroll
            for (int f = 0; f < 4; ++f)
                #pragma unroll
                for (int g = 0; g < 4; ++g)
                    acc[f][g] = __builtin_amdgcn_mfma_f32_16x16x32_bf16(af[f], bfr[g], acc[f][g], 0, 0, 0);
        }
    }
    const int orow = (l >> 4) * 4, ocol = l & 15;
    #pragma unroll
    for (int f = 0; f < 4; ++f) {
        #pragma unroll
        for (int g = 0; g < 4; ++g) {
            #pragma unroll
            for (int j = 0; j < 4; ++j) {
                const int m = m0 + wm + f * 16 + orow + j;
                const int nn = n0 + wn + g * 16 + ocol;
                Cp[((size_t)sk * 256 + m) * 1024 + nn] = f2bf(acc[f][g][j]);
            }
        }
    }
}

// ---------------- K6: fused split-K reduce + bias + lrelu + FC2 ------------------
// Thread t owns nn = 4t..4t+3: one uint2 (4 bf16) load per sk partial.
__global__ __launch_bounds__(256) void k6_fc2(const unsigned short* __restrict__ Cp,
                                              const float* __restrict__ bias,
                                              const float* __restrict__ w,
                                              const float* __restrict__ b,
                                              float* __restrict__ out) {
    const int n = blockIdx.x, t = threadIdx.x;
    const int nn0 = t * 4;
    float s0 = 0.f, s1 = 0.f, s2 = 0.f, s3 = 0.f;
    #pragma unroll
    for (int sk = 0; sk < 32; ++sk) {
        const uint2 u = *(const uint2*)(Cp + ((size_t)sk * 256 + n) * 1024 + nn0);
        s0 += bflo(u.x); s1 += bfhi(u.x); s2 += bflo(u.y); s3 += bfhi(u.y);
    }
    const float4 bi = *(const float4*)(bias + nn0);
    const float4 wv = *(const float4*)(w + nn0);
    float part = lrelu(s0 + bi.x) * wv.x + lrelu(s1 + bi.y) * wv.y +
                 lrelu(s2 + bi.z) * wv.z + lrelu(s3 + bi.w) * wv.w;
    const float2 red = block_reduce_sum2(part, 0.f);
    if (t == 0) out[n] = red.x + b[0];
}

extern "C" void kernel_launch(void* const* d_in, const int* in_sizes, int n_in,
                              void* d_out, int out_size, void* d_ws, size_t ws_size,
                              hipStream_t stream) {
    (void)in_sizes; (void)n_in; (void)out_size; (void)ws_size;
    const float* x    = (const float*)d_in[0];
    // labels (d_in[1]) and conv biases (d_in[3,5,7,9]) cancel exactly under InstanceNorm
    const float* w1   = (const float*)d_in[2];
    const float* w2   = (const float*)d_in[4];
    const float* w3   = (const float*)d_in[6];
    const float* w4   = (const float*)d_in[8];
    const float* fcw1 = (const float*)d_in[10];
    const float* fcb1 = (const float*)d_in[11];
    const float* fcw2 = (const float*)d_in[12];
    const float* fcb2 = (const float*)d_in[13];
    float* out = (float*)d_out;
    float* bufA = (float*)d_ws;                    // 16.7M floats
    float* bufB = bufA + 16777216;                 //  8.4M floats
    unsigned short* h4 = (unsigned short*)bufB;    // standard, 2.1M shorts
    unsigned short* wk = (unsigned short*)bufB + 12582912;  // 43008 shorts, clear of h4
    unsigned short* Cp = (unsigned short*)bufA;    // 32*256*1024 bf16 = 16.8 MB
    wprep<<<42, 1024, 0, stream>>>(w2, w3, w4, wk);
    k1234<<<256, 1024, 0, stream>>>(x, w1, wk, h4);
    k5_fc1<<<512, 256, 0, stream>>>(h4, fcw1, Cp);
    k6_fc2<<<256, 256, 0, stream>>>(Cp, fcb1, fcw2, fcb2, out);
}